// Round 4
// baseline (808.943 us; speedup 1.0000x reference)
//
#include <hip/hip_runtime.h>
#include <hip/hip_bf16.h>

#define NB    128
#define CENC  2048
#define FIN   512
#define FHID  8
#define S2D   49
#define SO3D  455
#define HW    49

typedef unsigned short ushort_t;
typedef __bf16 bf16x8 __attribute__((ext_vector_type(8)));
typedef float  f32x4  __attribute__((ext_vector_type(4)));

__device__ __forceinline__ int soff(int l) { return l*(4*l*l-1)/3; }

__device__ __forceinline__ ushort_t f2bf(float x) {
  __hip_bfloat16 h = __float2bfloat16(x);
  return *reinterpret_cast<ushort_t*>(&h);
}

// ---------- small fp32 GEMM (prep only): C = alpha * A@B ----------
__global__ __launch_bounds__(256) void gemm_nn(
    const float* __restrict__ A, const float* __restrict__ B, float* __restrict__ C,
    int M, int N, int K, int lda, int ldb, int ldc, float alpha)
{
  __shared__ float As[32*68];
  __shared__ float Bs[32*68];
  const int tid = threadIdx.x;
  const int tx = tid & 15, ty = tid >> 4;
  const int n0 = blockIdx.x * 64, m0 = blockIdx.y * 64;
  float acc[4][4] = {};
  for (int k0 = 0; k0 < K; k0 += 32) {
    {
      const int kk = tid & 31, mmB = tid >> 5;
      #pragma unroll
      for (int j = 0; j < 8; ++j) {
        const int mm = mmB + 8*j;
        const int m = m0 + mm, k = k0 + kk;
        As[kk*68 + mm] = (m < M && k < K) ? A[(size_t)m*lda + k] : 0.f;
      }
    }
    {
      const int nn = tid & 63, kkB = tid >> 6;
      #pragma unroll
      for (int j = 0; j < 8; ++j) {
        const int kk = kkB + 4*j;
        const int n = n0 + nn, k = k0 + kk;
        Bs[kk*68 + nn] = (n < N && k < K) ? B[(size_t)k*ldb + n] : 0.f;
      }
    }
    __syncthreads();
    #pragma unroll
    for (int kk = 0; kk < 32; ++kk) {
      const float4 a4 = *(const float4*)&As[kk*68 + ty*4];
      const float4 b4 = *(const float4*)&Bs[kk*68 + tx*4];
      const float av[4] = {a4.x,a4.y,a4.z,a4.w};
      const float bv[4] = {b4.x,b4.y,b4.z,b4.w};
      #pragma unroll
      for (int i = 0; i < 4; ++i)
        #pragma unroll
        for (int j = 0; j < 4; ++j)
          acc[i][j] = fmaf(av[i], bv[j], acc[i][j]);
    }
    __syncthreads();
  }
  #pragma unroll
  for (int i = 0; i < 4; ++i) {
    const int m = m0 + ty*4 + i;
    if (m >= M) continue;
    #pragma unroll
    for (int j = 0; j < 4; ++j) {
      const int n = n0 + tx*4 + j;
      if (n >= N) continue;
      C[(size_t)m*ldc + n] = acc[i][j] * alpha;
    }
  }
}

// ---------- fp32 -> bf16 elementwise (conv_w) ----------
__global__ void cvt_bf16(const float* __restrict__ in, ushort_t* __restrict__ out, int n4) {
  int i = (blockIdx.x*256 + threadIdx.x)*4;
  if (i < n4) {
    float4 v = *(const float4*)&in[i];
    out[i+0] = f2bf(v.x); out[i+1] = f2bf(v.y);
    out[i+2] = f2bf(v.z); out[i+3] = f2bf(v.w);
  }
}

// ---------- transpose + cvt + pad: in fp32 [R][C] -> out bf16 [Cp][Rp] (zeros outside) ----------
__global__ __launch_bounds__(256) void transpose_cvt(
    const float* __restrict__ in, int R, int C,
    ushort_t* __restrict__ out, int Rp, int Cp)
{
  __shared__ float t[32][33];
  const int c0 = blockIdx.x*32, r0 = blockIdx.y*32;
  const int tx = threadIdx.x & 31, ty = threadIdx.x >> 5;
  #pragma unroll
  for (int j = 0; j < 4; ++j) {
    const int r = r0 + ty + j*8, c = c0 + tx;
    t[ty + j*8][tx] = (r < R && c < C) ? in[(size_t)r*C + c] : 0.f;
  }
  __syncthreads();
  #pragma unroll
  for (int j = 0; j < 4; ++j) {
    const int c = c0 + ty + j*8, r = r0 + tx;
    if (c < Cp && r < Rp) out[(size_t)c*Rp + r] = f2bf(t[tx][ty + j*8]);
  }
}

// ---------- fmapPT[b][i(64)][c] = bf16( sum_hw fmap[b,c,hw] * P[hw,i] ), i>=49 -> 0 ----------
// v2: LDS-staged, fully coalesced. grid (CENC/64=32, NB). block 256.
// fmap[b][c0:c0+64][0:49] is a FLAT contiguous 3136-float range -> float4 copy to LDS.
// Register row read: lane stride 49 floats -> 17 banks mod 32, gcd(17,32)=1 -> 2 lanes/bank (free).
// block(0,0) also writes sumP[i] = sum_hw P[hw,i] (0 for i>=49).
__global__ __launch_bounds__(256) void prep_fmapPT(
    const float* __restrict__ fmap, const float* __restrict__ P,
    float* __restrict__ sumP, ushort_t* __restrict__ out)
{
  __shared__ float Fs[64*49];   // [c_local][hw], flat copy of global
  __shared__ float Ps[49*49];   // [hw][i], flat copy (broadcast reads -> no conflicts)
  const int tid = threadIdx.x;
  const int cc = blockIdx.x, b = blockIdx.y;
  const int c0 = cc*64;

  const float* fsrc = fmap + ((size_t)b*CENC + c0)*HW;   // 3136 floats, 16B-aligned
  for (int idx = tid; idx < 784; idx += 256)
    *(float4*)&Fs[idx*4] = *(const float4*)&fsrc[idx*4];
  for (int idx = tid; idx < 2401; idx += 256)
    Ps[idx] = P[idx];
  __syncthreads();

  if (b == 0 && cc == 0 && tid < 64) {
    float s = 0.f;
    if (tid < 49) for (int hw = 0; hw < 49; ++hw) s += Ps[hw*49 + tid];
    sumP[tid] = (tid < 49) ? s : 0.f;
  }

  const int cl = tid & 63, g = tid >> 6;   // g in 0..3 -> i range [g*16, g*16+16)
  float fm[49];
  #pragma unroll
  for (int h = 0; h < 49; ++h) fm[h] = Fs[cl*49 + h];

  ushort_t* op = out + (size_t)b*64*CENC + c0 + cl;
  #pragma unroll
  for (int ii = 0; ii < 16; ++ii) {
    const int i = g*16 + ii;
    if (i < 49) {
      float s = 0.f;
      #pragma unroll 7
      for (int hw = 0; hw < 49; ++hw) s = fmaf(fm[hw], Ps[hw*49 + i], s);
      op[(size_t)i*CENC] = f2bf(s);
    } else {
      op[(size_t)i*CENC] = 0;
    }
  }
}

// ---------- bf16 MFMA NT GEMM: C[m,n] = sum_k A[m,k]*B[n,k] ----------
// A bf16 [M][lda], B bf16 [N][ldb] (pre-transposed), 128x128 tile, BK=64, 4 waves.
// mode 0: fp32 store, optional rank-1 bias biasRow[m]*biasCol[n&63]
// mode 1: relu -> bf16 store
// mode 2: split-K fp32 partial (blockIdx.z, kPartLen), plain store
#define LSTR 72
__global__ __launch_bounds__(256, 2) void gemm_bf16_nt(
    const ushort_t* __restrict__ A, const ushort_t* __restrict__ B, void* __restrict__ Cv,
    int M, int N, int K, int lda, int ldb, int ldc,
    int mode, const float* __restrict__ biasRow, const float* __restrict__ biasCol,
    int kPartLen)
{
  __shared__ ushort_t Alds[128*LSTR];
  __shared__ ushort_t Blds[128*LSTR];
  const int tid  = threadIdx.x;
  const int wave = tid >> 6, lane = tid & 63;
  const int wm = wave >> 1, wn = wave & 1;
  const int col = lane & 15, quad = lane >> 4;
  const int m0 = blockIdx.y * 128, n0 = blockIdx.x * 128;
  int kStart = 0, kEnd = K;
  float*    C  = (float*)Cv;
  ushort_t* Cb = (ushort_t*)Cv;
  if (mode == 2) {
    kStart = blockIdx.z * kPartLen;
    kEnd = min(K, kStart + kPartLen);
    C += (size_t)blockIdx.z * (size_t)M * (size_t)ldc;
  }

  f32x4 acc[4][4];
  #pragma unroll
  for (int i = 0; i < 4; ++i)
    #pragma unroll
    for (int j = 0; j < 4; ++j)
      acc[i][j] = (f32x4){0.f,0.f,0.f,0.f};

  for (int k0 = kStart; k0 < kEnd; k0 += 64) {
    #pragma unroll
    for (int r = 0; r < 4; ++r) {
      const int u = tid + 256*r;
      const int mm = u >> 3, kg = u & 7;
      *(uint4*)&Alds[mm*LSTR + kg*8] = *(const uint4*)&A[(size_t)(m0+mm)*lda + k0 + kg*8];
      *(uint4*)&Blds[mm*LSTR + kg*8] = *(const uint4*)&B[(size_t)(n0+mm)*ldb + k0 + kg*8];
    }
    __syncthreads();
    #pragma unroll
    for (int ks = 0; ks < 2; ++ks) {
      bf16x8 af[4], bfr[4];
      #pragma unroll
      for (int t = 0; t < 4; ++t) {
        af[t]  = *(bf16x8*)&Alds[(wm*64 + t*16 + col)*LSTR + ks*32 + quad*8];
        bfr[t] = *(bf16x8*)&Blds[(wn*64 + t*16 + col)*LSTR + ks*32 + quad*8];
      }
      #pragma unroll
      for (int i = 0; i < 4; ++i)
        #pragma unroll
        for (int j = 0; j < 4; ++j)
          acc[i][j] = __builtin_amdgcn_mfma_f32_16x16x32_bf16(af[i], bfr[j], acc[i][j], 0, 0, 0);
    }
    __syncthreads();
  }

  // epilogue: C/D layout col = lane&15, row = quad*4 + reg
  #pragma unroll
  for (int i = 0; i < 4; ++i) {
    const int mBase = m0 + wm*64 + i*16 + quad*4;
    #pragma unroll
    for (int j = 0; j < 4; ++j) {
      const int n = n0 + wn*64 + j*16 + col;
      if (mode == 1) {
        #pragma unroll
        for (int r = 0; r < 4; ++r)
          Cb[(size_t)(mBase+r)*ldc + n] = f2bf(fmaxf(acc[i][j][r], 0.f));
      } else if (biasRow) {
        const float bc = biasCol[n & 63];
        #pragma unroll
        for (int r = 0; r < 4; ++r)
          C[(size_t)(mBase+r)*ldc + n] = acc[i][j][r] + biasRow[mBase+r]*bc;
      } else {
        #pragma unroll
        for (int r = 0; r < 4; ++r)
          C[(size_t)(mBase+r)*ldc + n] = acc[i][j][r];
      }
    }
  }
}

// ---------- zero y_pad columns [455,512) ----------
__global__ void zero_ypad(ushort_t* __restrict__ y) {
  const int idx = blockIdx.x*256 + threadIdx.x;
  if (idx < 1024*57) {
    const int r = idx / 57, c = 455 + idx % 57;
    y[r*512 + c] = 0;
  }
}

// ---------- s2 -> so3 linear (reads x3T fp32 [512][8192], writes y_pad bf16 [1024][512]) ----------
__global__ __launch_bounds__(256) void s2_to_so3(
    const float* __restrict__ x3T, const float* __restrict__ psi, ushort_t* __restrict__ y)
{
  __shared__ float Xs[4*32*16];
  __shared__ float Ps[32*8*16];
  const int tid = threadIdx.x;
  const int l = blockIdx.x;
  const int d = 2*l + 1;
  const int s2o = l*l;
  const int so = soff(l);
  const int b0 = blockIdx.y * 4;
  const int mhCnt = (d + 7) / 8;
  const int T = 4 * d * mhCnt;
  const bool valid = tid < T;
  int tb = 0, tu = 0, tmh = 0;
  if (valid) {
    tb = tid / (d*mhCnt);
    const int r = tid - tb*(d*mhCnt);
    tu = r / mhCnt;
    tmh = r - tu*mhCnt;
  }

  float acc[8][8] = {};
  const float invSqF = 0.044194173824159216f;  // 1/sqrt(512)

  for (int fc = 0; fc < FIN; fc += 32) {
    const int totX = 4*32*d;
    for (int idx = tid; idx < totX; idx += 256) {
      const int bl = idx / (32*d);
      const int r = idx - bl*(32*d);
      const int fl = r / d;
      const int m = r - fl*d;
      Xs[(bl*32 + fl)*16 + m] = x3T[(size_t)(fc+fl)*8192 + (b0+bl)*64 + s2o + m];
    }
    const int totP = 32*8*d;
    for (int idx = tid; idx < totP; idx += 256) {
      const int fl = idx / (8*d);
      const int r = idx - fl*(8*d);
      const int g = r / d;
      const int u = r - g*d;
      Ps[(fl*8 + g)*16 + u] = psi[((size_t)(fc+fl)*8 + g)*S2D + s2o + u];
    }
    __syncthreads();
    if (valid) {
      for (int fl = 0; fl < 32; ++fl) {
        const float4 xa = *(const float4*)&Xs[(tb*32 + fl)*16 + tmh*8];
        const float4 xb = *(const float4*)&Xs[(tb*32 + fl)*16 + tmh*8 + 4];
        const float xv[8] = {xa.x,xa.y,xa.z,xa.w,xb.x,xb.y,xb.z,xb.w};
        #pragma unroll
        for (int g = 0; g < 8; ++g) {
          const float pv = Ps[(fl*8 + g)*16 + tu];
          #pragma unroll
          for (int mm = 0; mm < 8; ++mm)
            acc[g][mm] = fmaf(pv, xv[mm], acc[g][mm]);
        }
      }
    }
    __syncthreads();
  }

  if (valid) {
    #pragma unroll
    for (int g = 0; g < 8; ++g) {
      for (int mm = 0; mm < 8; ++mm) {
        const int m = tmh*8 + mm;
        if (m < d)
          y[((size_t)(b0+tb)*8 + g)*512 + so + tu*d + m] = f2bf(acc[g][mm] * invSqF);
      }
    }
  }
}

// ---------- final so3 conv: 8-partial sum + per-l contraction + fp32 store ----------
__global__ __launch_bounds__(512) void so3_final(
    const float* __restrict__ zpart, const float* __restrict__ psi2,
    float* __restrict__ out)
{
  __shared__ float Zs[8*SO3D];
  __shared__ float P2s[8*SO3D];
  const int b = blockIdx.x, tid = threadIdx.x;
  for (int idx = tid; idx < 8*SO3D; idx += 512) {
    const int f = idx / SO3D, i = idx - f*SO3D;
    float s = 0.f;
    #pragma unroll
    for (int p = 0; p < 8; ++p)
      s += zpart[((size_t)p*1024 + (size_t)b*FHID + f)*512 + i];
    Zs[idx] = s;
    P2s[idx] = psi2[idx];
  }
  __syncthreads();
  if (tid < SO3D) {
    const int i = tid;
    int l;
    if (i < 1) l = 0; else if (i < 10) l = 1; else if (i < 35) l = 2;
    else if (i < 84) l = 3; else if (i < 165) l = 4; else if (i < 286) l = 5; else l = 6;
    const int so = soff(l), d = 2*l+1;
    const int r = i - so;
    const int v = r / d, m = r - v*d;
    float acc = 0.f;
    for (int f = 0; f < 8; ++f)
      for (int u = 0; u < d; ++u)
        acc = fmaf(Zs[f*SO3D + so + u*d + m], P2s[f*SO3D + so + u*d + v], acc);
    const float scale = rsqrtf(8.0f * (float)d);
    out[(size_t)b*SO3D + i] = acc * scale;
  }
}

extern "C" void kernel_launch(void* const* d_in, const int* in_sizes, int n_in,
                              void* d_out, int out_size, void* d_ws, size_t ws_size,
                              hipStream_t stream) {
  const float* fmap    = (const float*)d_in[0];
  const float* conv_w  = (const float*)d_in[1];
  const float* conv_b  = (const float*)d_in[2];
  const float* proj_w  = (const float*)d_in[3];
  const float* proj_Y  = (const float*)d_in[4];
  const float* fs_w    = (const float*)d_in[5];
  const float* fs_Y    = (const float*)d_in[6];
  const float* act_to  = (const float*)d_in[7];
  const float* act_from= (const float*)d_in[8];
  const float* so3_w   = (const float*)d_in[9];
  const float* so3_D   = (const float*)d_in[10];
  float* out           = (float*)d_out;

  // byte-offset workspace layout (aliasing by lifetime), total ~59.8 MB
  char* wsb = (char*)d_ws;
  float*    wP       = (float*)(wsb + 0);          //  49x49 fp32
  float*    wSumP    = (float*)(wsb + 9728);       //  64 fp32
  float*    wPsi     = (float*)(wsb + 9984);       //  4096x49 fp32
  float*    wPsi2    = (float*)(wsb + 812800);     //  8x455 fp32
  ushort_t* cwB      = (ushort_t*)(wsb + 827392);  //  512x2048 bf16
  ushort_t* actToT   = (ushort_t*)(wsb + 2924544); //  4096x512 bf16
  ushort_t* actFromT = (ushort_t*)(wsb + 7118848); //  512x4096 bf16
  ushort_t* yPad     = (ushort_t*)(wsb + 11313152);//  1024x512 bf16
  ushort_t* fmapPT   = (ushort_t*)(wsb + 12361728);//  8192x2048 bf16 (dead after conv gemm)
  float*    zPart    = (float*)(wsb + 12361728);   //  8x1024x512 fp32, aliases fmapPT
  float*    wX3T     = (float*)(wsb + 45916160);   //  512x8192 fp32 (dead after s2_to_so3)
  ushort_t* gBuf     = (ushort_t*)(wsb + 45916160);//  1024x4096 bf16, aliases wX3T

  const float is192 = 0.07216878364870323f;  // 1/sqrt(192)

  // prep (fp32 smalls + bf16 conversions)
  gemm_nn<<<dim3(1,1), 256, 0, stream>>>(proj_w, proj_Y, wP, 49,49,192, 192,49,49, is192);
  gemm_nn<<<dim3(1,64), 256, 0, stream>>>(fs_w, fs_Y, wPsi, 4096,49,192, 192,49,49, is192);
  gemm_nn<<<dim3(8,1), 256, 0, stream>>>(so3_w, so3_D, wPsi2, 8,455,192, 192,455,455, is192);
  cvt_bf16<<<dim3(1024), 256, 0, stream>>>(conv_w, cwB, 512*2048);
  transpose_cvt<<<dim3(128,16), 256, 0, stream>>>(act_to, 455, 4000, actToT, 512, 4096);
  transpose_cvt<<<dim3(16,128), 256, 0, stream>>>(act_from, 4000, 455, actFromT, 4096, 512);
  prep_fmapPT<<<dim3(32,128), 256, 0, stream>>>(fmap, wP, wSumP, fmapPT);
  zero_ypad<<<dim3(228), 256, 0, stream>>>(yPad);

  // x3T[f][(b,i)] = cwB @ fmapPT^T + conv_b[f]*sumP[i]   (M=512, N=8192, K=2048)
  gemm_bf16_nt<<<dim3(64,4), 256, 0, stream>>>(cwB, fmapPT, wX3T,
      512, 8192, 2048, 2048, 2048, 8192, 0, conv_b, wSumP, 0);
  // y = s2->so3 linear (bf16 out into yPad)
  s2_to_so3<<<dim3(7,32), 256, 0, stream>>>(wX3T, wPsi, yPad);
  // g = relu(yPad @ actToT^T) bf16   (M=1024, N=4096, K=512)
  gemm_bf16_nt<<<dim3(32,8), 256, 0, stream>>>(yPad, actToT, gBuf,
      1024, 4096, 512, 512, 512, 4096, 1, nullptr, nullptr, 0);
  // zPart = g @ actFromT^T, split-K=8   (M=1024, N=512, K=4096)
  gemm_bf16_nt<<<dim3(4,8,8), 256, 0, stream>>>(gBuf, actFromT, zPart,
      1024, 512, 4096, 4096, 4096, 512, 2, nullptr, nullptr, 512);
  // final contraction + fp32 store
  so3_final<<<dim3(128), 512, 0, stream>>>(zPart, wPsi2, out);
}

// Round 5
// 446.426 us; speedup vs baseline: 1.8120x; 1.8120x over previous
//
#include <hip/hip_runtime.h>
#include <hip/hip_bf16.h>

#define NB    128
#define CENC  2048
#define FIN   512
#define FHID  8
#define S2D   49
#define SO3D  455
#define HW    49

typedef unsigned short ushort_t;
typedef __bf16 bf16x8 __attribute__((ext_vector_type(8)));
typedef float  f32x4  __attribute__((ext_vector_type(4)));

__device__ __forceinline__ int soff(int l) { return l*(4*l*l-1)/3; }

__device__ __forceinline__ ushort_t f2bf(float x) {
  __hip_bfloat16 h = __float2bfloat16(x);
  return *reinterpret_cast<ushort_t*>(&h);
}

// ---------- small fp32 GEMM (prep only): C = alpha * A@B ----------
__global__ __launch_bounds__(256) void gemm_nn(
    const float* __restrict__ A, const float* __restrict__ B, float* __restrict__ C,
    int M, int N, int K, int lda, int ldb, int ldc, float alpha)
{
  __shared__ float As[32*68];
  __shared__ float Bs[32*68];
  const int tid = threadIdx.x;
  const int tx = tid & 15, ty = tid >> 4;
  const int n0 = blockIdx.x * 64, m0 = blockIdx.y * 64;
  float acc[4][4] = {};
  for (int k0 = 0; k0 < K; k0 += 32) {
    {
      const int kk = tid & 31, mmB = tid >> 5;
      #pragma unroll
      for (int j = 0; j < 8; ++j) {
        const int mm = mmB + 8*j;
        const int m = m0 + mm, k = k0 + kk;
        As[kk*68 + mm] = (m < M && k < K) ? A[(size_t)m*lda + k] : 0.f;
      }
    }
    {
      const int nn = tid & 63, kkB = tid >> 6;
      #pragma unroll
      for (int j = 0; j < 8; ++j) {
        const int kk = kkB + 4*j;
        const int n = n0 + nn, k = k0 + kk;
        Bs[kk*68 + nn] = (n < N && k < K) ? B[(size_t)k*ldb + n] : 0.f;
      }
    }
    __syncthreads();
    #pragma unroll
    for (int kk = 0; kk < 32; ++kk) {
      const float4 a4 = *(const float4*)&As[kk*68 + ty*4];
      const float4 b4 = *(const float4*)&Bs[kk*68 + tx*4];
      const float av[4] = {a4.x,a4.y,a4.z,a4.w};
      const float bv[4] = {b4.x,b4.y,b4.z,b4.w};
      #pragma unroll
      for (int i = 0; i < 4; ++i)
        #pragma unroll
        for (int j = 0; j < 4; ++j)
          acc[i][j] = fmaf(av[i], bv[j], acc[i][j]);
    }
    __syncthreads();
  }
  #pragma unroll
  for (int i = 0; i < 4; ++i) {
    const int m = m0 + ty*4 + i;
    if (m >= M) continue;
    #pragma unroll
    for (int j = 0; j < 4; ++j) {
      const int n = n0 + tx*4 + j;
      if (n >= N) continue;
      C[(size_t)m*ldc + n] = acc[i][j] * alpha;
    }
  }
}

// ---------- fp32 -> bf16 elementwise (conv_w) ----------
__global__ void cvt_bf16(const float* __restrict__ in, ushort_t* __restrict__ out, int n4) {
  int i = (blockIdx.x*256 + threadIdx.x)*4;
  if (i < n4) {
    float4 v = *(const float4*)&in[i];
    out[i+0] = f2bf(v.x); out[i+1] = f2bf(v.y);
    out[i+2] = f2bf(v.z); out[i+3] = f2bf(v.w);
  }
}

// ---------- transpose + cvt + pad: in fp32 [R][C] -> out bf16 [Cp][Rp] (zeros outside) ----------
__global__ __launch_bounds__(256) void transpose_cvt(
    const float* __restrict__ in, int R, int C,
    ushort_t* __restrict__ out, int Rp, int Cp)
{
  __shared__ float t[32][33];
  const int c0 = blockIdx.x*32, r0 = blockIdx.y*32;
  const int tx = threadIdx.x & 31, ty = threadIdx.x >> 5;
  #pragma unroll
  for (int j = 0; j < 4; ++j) {
    const int r = r0 + ty + j*8, c = c0 + tx;
    t[ty + j*8][tx] = (r < R && c < C) ? in[(size_t)r*C + c] : 0.f;
  }
  __syncthreads();
  #pragma unroll
  for (int j = 0; j < 4; ++j) {
    const int c = c0 + ty + j*8, r = r0 + tx;
    if (c < Cp && r < Rp) out[(size_t)c*Rp + r] = f2bf(t[tx][ty + j*8]);
  }
}

// ---------- fmapPT[b][i(64)][c] = bf16( sum_hw fmap[b,c,hw] * P[hw,i] ), i>=49 -> 0 ----------
// v3: no per-thread hw-array (v2's dynamically-indexed fm[49] was demoted to SCRATCH ->
// ~1.2 GB of spill traffic; VGPR_Count=36 < 49 was the tell). Now: 16 i-accumulators
// (statically unrolled -> registers), stream h; per h: 1 ds_read_b32 (Fs, 2-way free)
// + 4 broadcast ds_read_b128 (Ps, [49][64] layout, 16B aligned, i>=49 zero-padded).
// grid (CENC/64=32, NB). block 256.
__global__ __launch_bounds__(256) void prep_fmapPT(
    const float* __restrict__ fmap, const float* __restrict__ P,
    float* __restrict__ sumP, ushort_t* __restrict__ out)
{
  __shared__ float Fs[64*49];   // [c_local][hw], flat coalesced copy
  __shared__ float Ps[49*64];   // [hw][i(64)], zeros for i>=49
  const int tid = threadIdx.x;
  const int cc = blockIdx.x, b = blockIdx.y;
  const int c0 = cc*64;

  const float* fsrc = fmap + ((size_t)b*CENC + c0)*HW;   // 3136 floats, contiguous
  for (int idx = tid; idx < 784; idx += 256)
    *(float4*)&Fs[idx*4] = *(const float4*)&fsrc[idx*4];
  for (int idx = tid; idx < 49*64; idx += 256) {
    const int h = idx >> 6, i = idx & 63;
    Ps[idx] = (i < 49) ? P[h*49 + i] : 0.f;
  }
  __syncthreads();

  if (b == 0 && cc == 0 && tid < 64) {
    float s = 0.f;
    if (tid < 49) for (int hw = 0; hw < 49; ++hw) s += P[hw*49 + tid];
    sumP[tid] = (tid < 49) ? s : 0.f;
  }

  const int cl = tid & 63, g = tid >> 6;   // lane -> c, wave -> i-group of 16
  float acc[16];
  #pragma unroll
  for (int ii = 0; ii < 16; ++ii) acc[ii] = 0.f;

  #pragma unroll 7
  for (int h = 0; h < 49; ++h) {
    const float fv = Fs[cl*49 + h];
    const float4 p0 = *(const float4*)&Ps[h*64 + g*16 + 0];
    const float4 p1 = *(const float4*)&Ps[h*64 + g*16 + 4];
    const float4 p2 = *(const float4*)&Ps[h*64 + g*16 + 8];
    const float4 p3 = *(const float4*)&Ps[h*64 + g*16 + 12];
    acc[ 0] = fmaf(fv, p0.x, acc[ 0]);
    acc[ 1] = fmaf(fv, p0.y, acc[ 1]);
    acc[ 2] = fmaf(fv, p0.z, acc[ 2]);
    acc[ 3] = fmaf(fv, p0.w, acc[ 3]);
    acc[ 4] = fmaf(fv, p1.x, acc[ 4]);
    acc[ 5] = fmaf(fv, p1.y, acc[ 5]);
    acc[ 6] = fmaf(fv, p1.z, acc[ 6]);
    acc[ 7] = fmaf(fv, p1.w, acc[ 7]);
    acc[ 8] = fmaf(fv, p2.x, acc[ 8]);
    acc[ 9] = fmaf(fv, p2.y, acc[ 9]);
    acc[10] = fmaf(fv, p2.z, acc[10]);
    acc[11] = fmaf(fv, p2.w, acc[11]);
    acc[12] = fmaf(fv, p3.x, acc[12]);
    acc[13] = fmaf(fv, p3.y, acc[13]);
    acc[14] = fmaf(fv, p3.z, acc[14]);
    acc[15] = fmaf(fv, p3.w, acc[15]);
  }

  ushort_t* op = out + (size_t)b*64*CENC + c0 + cl;
  #pragma unroll
  for (int ii = 0; ii < 16; ++ii)
    op[(size_t)(g*16 + ii)*CENC] = f2bf(acc[ii]);   // i>=49 -> Ps pad zeros -> writes 0
}

// ---------- bf16 MFMA NT GEMM: C[m,n] = sum_k A[m,k]*B[n,k] ----------
// A bf16 [M][lda], B bf16 [N][ldb] (pre-transposed), 128x128 tile, BK=64, 4 waves.
// mode 0: fp32 store, optional rank-1 bias biasRow[m]*biasCol[n&63]
// mode 1: relu -> bf16 store
// mode 2: split-K fp32 partial (blockIdx.z, kPartLen), plain store
#define LSTR 72
__global__ __launch_bounds__(256, 2) void gemm_bf16_nt(
    const ushort_t* __restrict__ A, const ushort_t* __restrict__ B, void* __restrict__ Cv,
    int M, int N, int K, int lda, int ldb, int ldc,
    int mode, const float* __restrict__ biasRow, const float* __restrict__ biasCol,
    int kPartLen)
{
  __shared__ ushort_t Alds[128*LSTR];
  __shared__ ushort_t Blds[128*LSTR];
  const int tid  = threadIdx.x;
  const int wave = tid >> 6, lane = tid & 63;
  const int wm = wave >> 1, wn = wave & 1;
  const int col = lane & 15, quad = lane >> 4;
  const int m0 = blockIdx.y * 128, n0 = blockIdx.x * 128;
  int kStart = 0, kEnd = K;
  float*    C  = (float*)Cv;
  ushort_t* Cb = (ushort_t*)Cv;
  if (mode == 2) {
    kStart = blockIdx.z * kPartLen;
    kEnd = min(K, kStart + kPartLen);
    C += (size_t)blockIdx.z * (size_t)M * (size_t)ldc;
  }

  f32x4 acc[4][4];
  #pragma unroll
  for (int i = 0; i < 4; ++i)
    #pragma unroll
    for (int j = 0; j < 4; ++j)
      acc[i][j] = (f32x4){0.f,0.f,0.f,0.f};

  for (int k0 = kStart; k0 < kEnd; k0 += 64) {
    #pragma unroll
    for (int r = 0; r < 4; ++r) {
      const int u = tid + 256*r;
      const int mm = u >> 3, kg = u & 7;
      *(uint4*)&Alds[mm*LSTR + kg*8] = *(const uint4*)&A[(size_t)(m0+mm)*lda + k0 + kg*8];
      *(uint4*)&Blds[mm*LSTR + kg*8] = *(const uint4*)&B[(size_t)(n0+mm)*ldb + k0 + kg*8];
    }
    __syncthreads();
    #pragma unroll
    for (int ks = 0; ks < 2; ++ks) {
      bf16x8 af[4], bfr[4];
      #pragma unroll
      for (int t = 0; t < 4; ++t) {
        af[t]  = *(bf16x8*)&Alds[(wm*64 + t*16 + col)*LSTR + ks*32 + quad*8];
        bfr[t] = *(bf16x8*)&Blds[(wn*64 + t*16 + col)*LSTR + ks*32 + quad*8];
      }
      #pragma unroll
      for (int i = 0; i < 4; ++i)
        #pragma unroll
        for (int j = 0; j < 4; ++j)
          acc[i][j] = __builtin_amdgcn_mfma_f32_16x16x32_bf16(af[i], bfr[j], acc[i][j], 0, 0, 0);
    }
    __syncthreads();
  }

  // epilogue: C/D layout col = lane&15, row = quad*4 + reg
  #pragma unroll
  for (int i = 0; i < 4; ++i) {
    const int mBase = m0 + wm*64 + i*16 + quad*4;
    #pragma unroll
    for (int j = 0; j < 4; ++j) {
      const int n = n0 + wn*64 + j*16 + col;
      if (mode == 1) {
        #pragma unroll
        for (int r = 0; r < 4; ++r)
          Cb[(size_t)(mBase+r)*ldc + n] = f2bf(fmaxf(acc[i][j][r], 0.f));
      } else if (biasRow) {
        const float bc = biasCol[n & 63];
        #pragma unroll
        for (int r = 0; r < 4; ++r)
          C[(size_t)(mBase+r)*ldc + n] = acc[i][j][r] + biasRow[mBase+r]*bc;
      } else {
        #pragma unroll
        for (int r = 0; r < 4; ++r)
          C[(size_t)(mBase+r)*ldc + n] = acc[i][j][r];
      }
    }
  }
}

// ---------- zero y_pad columns [455,512) ----------
__global__ void zero_ypad(ushort_t* __restrict__ y) {
  const int idx = blockIdx.x*256 + threadIdx.x;
  if (idx < 1024*57) {
    const int r = idx / 57, c = 455 + idx % 57;
    y[r*512 + c] = 0;
  }
}

// ---------- s2 -> so3 linear (reads x3T fp32 [512][8192], writes y_pad bf16 [1024][512]) ----------
__global__ __launch_bounds__(256) void s2_to_so3(
    const float* __restrict__ x3T, const float* __restrict__ psi, ushort_t* __restrict__ y)
{
  __shared__ float Xs[4*32*16];
  __shared__ float Ps[32*8*16];
  const int tid = threadIdx.x;
  const int l = blockIdx.x;
  const int d = 2*l + 1;
  const int s2o = l*l;
  const int so = soff(l);
  const int b0 = blockIdx.y * 4;
  const int mhCnt = (d + 7) / 8;
  const int T = 4 * d * mhCnt;
  const bool valid = tid < T;
  int tb = 0, tu = 0, tmh = 0;
  if (valid) {
    tb = tid / (d*mhCnt);
    const int r = tid - tb*(d*mhCnt);
    tu = r / mhCnt;
    tmh = r - tu*mhCnt;
  }

  float acc[8][8] = {};
  const float invSqF = 0.044194173824159216f;  // 1/sqrt(512)

  for (int fc = 0; fc < FIN; fc += 32) {
    const int totX = 4*32*d;
    for (int idx = tid; idx < totX; idx += 256) {
      const int bl = idx / (32*d);
      const int r = idx - bl*(32*d);
      const int fl = r / d;
      const int m = r - fl*d;
      Xs[(bl*32 + fl)*16 + m] = x3T[(size_t)(fc+fl)*8192 + (b0+bl)*64 + s2o + m];
    }
    const int totP = 32*8*d;
    for (int idx = tid; idx < totP; idx += 256) {
      const int fl = idx / (8*d);
      const int r = idx - fl*(8*d);
      const int g = r / d;
      const int u = r - g*d;
      Ps[(fl*8 + g)*16 + u] = psi[((size_t)(fc+fl)*8 + g)*S2D + s2o + u];
    }
    __syncthreads();
    if (valid) {
      for (int fl = 0; fl < 32; ++fl) {
        const float4 xa = *(const float4*)&Xs[(tb*32 + fl)*16 + tmh*8];
        const float4 xb = *(const float4*)&Xs[(tb*32 + fl)*16 + tmh*8 + 4];
        const float xv[8] = {xa.x,xa.y,xa.z,xa.w,xb.x,xb.y,xb.z,xb.w};
        #pragma unroll
        for (int g = 0; g < 8; ++g) {
          const float pv = Ps[(fl*8 + g)*16 + tu];
          #pragma unroll
          for (int mm = 0; mm < 8; ++mm)
            acc[g][mm] = fmaf(pv, xv[mm], acc[g][mm]);
        }
      }
    }
    __syncthreads();
  }

  if (valid) {
    #pragma unroll
    for (int g = 0; g < 8; ++g) {
      for (int mm = 0; mm < 8; ++mm) {
        const int m = tmh*8 + mm;
        if (m < d)
          y[((size_t)(b0+tb)*8 + g)*512 + so + tu*d + m] = f2bf(acc[g][mm] * invSqF);
      }
    }
  }
}

// ---------- final so3 conv: 8-partial sum + per-l contraction + fp32 store ----------
__global__ __launch_bounds__(512) void so3_final(
    const float* __restrict__ zpart, const float* __restrict__ psi2,
    float* __restrict__ out)
{
  __shared__ float Zs[8*SO3D];
  __shared__ float P2s[8*SO3D];
  const int b = blockIdx.x, tid = threadIdx.x;
  for (int idx = tid; idx < 8*SO3D; idx += 512) {
    const int f = idx / SO3D, i = idx - f*SO3D;
    float s = 0.f;
    #pragma unroll
    for (int p = 0; p < 8; ++p)
      s += zpart[((size_t)p*1024 + (size_t)b*FHID + f)*512 + i];
    Zs[idx] = s;
    P2s[idx] = psi2[idx];
  }
  __syncthreads();
  if (tid < SO3D) {
    const int i = tid;
    int l;
    if (i < 1) l = 0; else if (i < 10) l = 1; else if (i < 35) l = 2;
    else if (i < 84) l = 3; else if (i < 165) l = 4; else if (i < 286) l = 5; else l = 6;
    const int so = soff(l), d = 2*l+1;
    const int r = i - so;
    const int v = r / d, m = r - v*d;
    float acc = 0.f;
    for (int f = 0; f < 8; ++f)
      for (int u = 0; u < d; ++u)
        acc = fmaf(Zs[f*SO3D + so + u*d + m], P2s[f*SO3D + so + u*d + v], acc);
    const float scale = rsqrtf(8.0f * (float)d);
    out[(size_t)b*SO3D + i] = acc * scale;
  }
}

extern "C" void kernel_launch(void* const* d_in, const int* in_sizes, int n_in,
                              void* d_out, int out_size, void* d_ws, size_t ws_size,
                              hipStream_t stream) {
  const float* fmap    = (const float*)d_in[0];
  const float* conv_w  = (const float*)d_in[1];
  const float* conv_b  = (const float*)d_in[2];
  const float* proj_w  = (const float*)d_in[3];
  const float* proj_Y  = (const float*)d_in[4];
  const float* fs_w    = (const float*)d_in[5];
  const float* fs_Y    = (const float*)d_in[6];
  const float* act_to  = (const float*)d_in[7];
  const float* act_from= (const float*)d_in[8];
  const float* so3_w   = (const float*)d_in[9];
  const float* so3_D   = (const float*)d_in[10];
  float* out           = (float*)d_out;

  // byte-offset workspace layout (aliasing by lifetime), total ~59.8 MB
  char* wsb = (char*)d_ws;
  float*    wP       = (float*)(wsb + 0);          //  49x49 fp32
  float*    wSumP    = (float*)(wsb + 9728);       //  64 fp32
  float*    wPsi     = (float*)(wsb + 9984);       //  4096x49 fp32
  float*    wPsi2    = (float*)(wsb + 812800);     //  8x455 fp32
  ushort_t* cwB      = (ushort_t*)(wsb + 827392);  //  512x2048 bf16
  ushort_t* actToT   = (ushort_t*)(wsb + 2924544); //  4096x512 bf16
  ushort_t* actFromT = (ushort_t*)(wsb + 7118848); //  512x4096 bf16
  ushort_t* yPad     = (ushort_t*)(wsb + 11313152);//  1024x512 bf16
  ushort_t* fmapPT   = (ushort_t*)(wsb + 12361728);//  8192x2048 bf16 (dead after conv gemm)
  float*    zPart    = (float*)(wsb + 12361728);   //  8x1024x512 fp32, aliases fmapPT
  float*    wX3T     = (float*)(wsb + 45916160);   //  512x8192 fp32 (dead after s2_to_so3)
  ushort_t* gBuf     = (ushort_t*)(wsb + 45916160);//  1024x4096 bf16, aliases wX3T

  const float is192 = 0.07216878364870323f;  // 1/sqrt(192)

  // prep (fp32 smalls + bf16 conversions)
  gemm_nn<<<dim3(1,1), 256, 0, stream>>>(proj_w, proj_Y, wP, 49,49,192, 192,49,49, is192);
  gemm_nn<<<dim3(1,64), 256, 0, stream>>>(fs_w, fs_Y, wPsi, 4096,49,192, 192,49,49, is192);
  gemm_nn<<<dim3(8,1), 256, 0, stream>>>(so3_w, so3_D, wPsi2, 8,455,192, 192,455,455, is192);
  cvt_bf16<<<dim3(1024), 256, 0, stream>>>(conv_w, cwB, 512*2048);
  transpose_cvt<<<dim3(128,16), 256, 0, stream>>>(act_to, 455, 4000, actToT, 512, 4096);
  transpose_cvt<<<dim3(16,128), 256, 0, stream>>>(act_from, 4000, 455, actFromT, 4096, 512);
  prep_fmapPT<<<dim3(32,128), 256, 0, stream>>>(fmap, wP, wSumP, fmapPT);
  zero_ypad<<<dim3(228), 256, 0, stream>>>(yPad);

  // x3T[f][(b,i)] = cwB @ fmapPT^T + conv_b[f]*sumP[i]   (M=512, N=8192, K=2048)
  gemm_bf16_nt<<<dim3(64,4), 256, 0, stream>>>(cwB, fmapPT, wX3T,
      512, 8192, 2048, 2048, 2048, 8192, 0, conv_b, wSumP, 0);
  // y = s2->so3 linear (bf16 out into yPad)
  s2_to_so3<<<dim3(7,32), 256, 0, stream>>>(wX3T, wPsi, yPad);
  // g = relu(yPad @ actToT^T) bf16   (M=1024, N=4096, K=512)
  gemm_bf16_nt<<<dim3(32,8), 256, 0, stream>>>(yPad, actToT, gBuf,
      1024, 4096, 512, 512, 512, 4096, 1, nullptr, nullptr, 0);
  // zPart = g @ actFromT^T, split-K=8   (M=1024, N=512, K=4096)
  gemm_bf16_nt<<<dim3(4,8,8), 256, 0, stream>>>(gBuf, actFromT, zPart,
      1024, 512, 4096, 4096, 4096, 512, 2, nullptr, nullptr, 512);
  // final contraction + fp32 store
  so3_final<<<dim3(128), 512, 0, stream>>>(zPart, wPsi2, out);
}

// Round 6
// 358.904 us; speedup vs baseline: 2.2539x; 1.2439x over previous
//
#include <hip/hip_runtime.h>
#include <hip/hip_bf16.h>

#define NB    128
#define CENC  2048
#define FIN   512
#define FHID  8
#define S2D   49
#define SO3D  455
#define HW    49

typedef unsigned short ushort_t;
typedef __bf16 bf16x8 __attribute__((ext_vector_type(8)));
typedef float  f32x4  __attribute__((ext_vector_type(4)));

__device__ __forceinline__ int soff(int l) { return l*(4*l*l-1)/3; }  // sum_{l'<l}(2l'+1)^2

__device__ __forceinline__ ushort_t f2bf(float x) {
  __hip_bfloat16 h = __float2bfloat16(x);
  return *reinterpret_cast<ushort_t*>(&h);
}

// ---------- small fp32 GEMM (prep only): C = alpha * A@B ----------
__global__ __launch_bounds__(256) void gemm_nn(
    const float* __restrict__ A, const float* __restrict__ B, float* __restrict__ C,
    int M, int N, int K, int lda, int ldb, int ldc, float alpha)
{
  __shared__ float As[32*68];
  __shared__ float Bs[32*68];
  const int tid = threadIdx.x;
  const int tx = tid & 15, ty = tid >> 4;
  const int n0 = blockIdx.x * 64, m0 = blockIdx.y * 64;
  float acc[4][4] = {};
  for (int k0 = 0; k0 < K; k0 += 32) {
    {
      const int kk = tid & 31, mmB = tid >> 5;
      #pragma unroll
      for (int j = 0; j < 8; ++j) {
        const int mm = mmB + 8*j;
        const int m = m0 + mm, k = k0 + kk;
        As[kk*68 + mm] = (m < M && k < K) ? A[(size_t)m*lda + k] : 0.f;
      }
    }
    {
      const int nn = tid & 63, kkB = tid >> 6;
      #pragma unroll
      for (int j = 0; j < 8; ++j) {
        const int kk = kkB + 4*j;
        const int n = n0 + nn, k = k0 + kk;
        Bs[kk*68 + nn] = (n < N && k < K) ? B[(size_t)k*ldb + n] : 0.f;
      }
    }
    __syncthreads();
    #pragma unroll
    for (int kk = 0; kk < 32; ++kk) {
      const float4 a4 = *(const float4*)&As[kk*68 + ty*4];
      const float4 b4 = *(const float4*)&Bs[kk*68 + tx*4];
      const float av[4] = {a4.x,a4.y,a4.z,a4.w};
      const float bv[4] = {b4.x,b4.y,b4.z,b4.w};
      #pragma unroll
      for (int i = 0; i < 4; ++i)
        #pragma unroll
        for (int j = 0; j < 4; ++j)
          acc[i][j] = fmaf(av[i], bv[j], acc[i][j]);
    }
    __syncthreads();
  }
  #pragma unroll
  for (int i = 0; i < 4; ++i) {
    const int m = m0 + ty*4 + i;
    if (m >= M) continue;
    #pragma unroll
    for (int j = 0; j < 4; ++j) {
      const int n = n0 + tx*4 + j;
      if (n >= N) continue;
      C[(size_t)m*ldc + n] = acc[i][j] * alpha;
    }
  }
}

// ---------- fp32 -> bf16 elementwise (conv_w) ----------
__global__ void cvt_bf16(const float* __restrict__ in, ushort_t* __restrict__ out, int n4) {
  int i = (blockIdx.x*256 + threadIdx.x)*4;
  if (i < n4) {
    float4 v = *(const float4*)&in[i];
    out[i+0] = f2bf(v.x); out[i+1] = f2bf(v.y);
    out[i+2] = f2bf(v.z); out[i+3] = f2bf(v.w);
  }
}

// ---------- transpose + cvt + pad: in fp32 [R][C] -> out bf16 [Cp][Rp] (zeros outside) ----------
__global__ __launch_bounds__(256) void transpose_cvt(
    const float* __restrict__ in, int R, int C,
    ushort_t* __restrict__ out, int Rp, int Cp)
{
  __shared__ float t[32][33];
  const int c0 = blockIdx.x*32, r0 = blockIdx.y*32;
  const int tx = threadIdx.x & 31, ty = threadIdx.x >> 5;
  #pragma unroll
  for (int j = 0; j < 4; ++j) {
    const int r = r0 + ty + j*8, c = c0 + tx;
    t[ty + j*8][tx] = (r < R && c < C) ? in[(size_t)r*C + c] : 0.f;
  }
  __syncthreads();
  #pragma unroll
  for (int j = 0; j < 4; ++j) {
    const int c = c0 + ty + j*8, r = r0 + tx;
    if (c < Cp && r < Rp) out[(size_t)c*Rp + r] = f2bf(t[tx][ty + j*8]);
  }
}

// ---------- fmapPT[b][i(64)][c] = bf16( sum_hw fmap[b,c,hw] * P[hw,i] ), i>=49 -> 0 ----------
// (R4 lesson: no dynamically-indexed per-thread arrays -> scratch demotion.)
__global__ __launch_bounds__(256) void prep_fmapPT(
    const float* __restrict__ fmap, const float* __restrict__ P,
    float* __restrict__ sumP, ushort_t* __restrict__ out)
{
  __shared__ float Fs[64*49];   // [c_local][hw], flat coalesced copy
  __shared__ float Ps[49*64];   // [hw][i(64)], zeros for i>=49
  const int tid = threadIdx.x;
  const int cc = blockIdx.x, b = blockIdx.y;
  const int c0 = cc*64;

  const float* fsrc = fmap + ((size_t)b*CENC + c0)*HW;   // 3136 floats, contiguous
  for (int idx = tid; idx < 784; idx += 256)
    *(float4*)&Fs[idx*4] = *(const float4*)&fsrc[idx*4];
  for (int idx = tid; idx < 49*64; idx += 256) {
    const int h = idx >> 6, i = idx & 63;
    Ps[idx] = (i < 49) ? P[h*49 + i] : 0.f;
  }
  __syncthreads();

  if (b == 0 && cc == 0 && tid < 64) {
    float s = 0.f;
    if (tid < 49) for (int hw = 0; hw < 49; ++hw) s += P[hw*49 + tid];
    sumP[tid] = (tid < 49) ? s : 0.f;
  }

  const int cl = tid & 63, g = tid >> 6;   // lane -> c, wave -> i-group of 16
  float acc[16];
  #pragma unroll
  for (int ii = 0; ii < 16; ++ii) acc[ii] = 0.f;

  #pragma unroll 7
  for (int h = 0; h < 49; ++h) {
    const float fv = Fs[cl*49 + h];
    const float4 p0 = *(const float4*)&Ps[h*64 + g*16 + 0];
    const float4 p1 = *(const float4*)&Ps[h*64 + g*16 + 4];
    const float4 p2 = *(const float4*)&Ps[h*64 + g*16 + 8];
    const float4 p3 = *(const float4*)&Ps[h*64 + g*16 + 12];
    acc[ 0] = fmaf(fv, p0.x, acc[ 0]);
    acc[ 1] = fmaf(fv, p0.y, acc[ 1]);
    acc[ 2] = fmaf(fv, p0.z, acc[ 2]);
    acc[ 3] = fmaf(fv, p0.w, acc[ 3]);
    acc[ 4] = fmaf(fv, p1.x, acc[ 4]);
    acc[ 5] = fmaf(fv, p1.y, acc[ 5]);
    acc[ 6] = fmaf(fv, p1.z, acc[ 6]);
    acc[ 7] = fmaf(fv, p1.w, acc[ 7]);
    acc[ 8] = fmaf(fv, p2.x, acc[ 8]);
    acc[ 9] = fmaf(fv, p2.y, acc[ 9]);
    acc[10] = fmaf(fv, p2.z, acc[10]);
    acc[11] = fmaf(fv, p2.w, acc[11]);
    acc[12] = fmaf(fv, p3.x, acc[12]);
    acc[13] = fmaf(fv, p3.y, acc[13]);
    acc[14] = fmaf(fv, p3.z, acc[14]);
    acc[15] = fmaf(fv, p3.w, acc[15]);
  }

  ushort_t* op = out + (size_t)b*64*CENC + c0 + cl;
  #pragma unroll
  for (int ii = 0; ii < 16; ++ii)
    op[(size_t)(g*16 + ii)*CENC] = f2bf(acc[ii]);
}

// ---------- psiT[(g*64 + itil)][f] = bf16(psi[f,g,itil]) , itil>=49 -> 0 ----------
__global__ __launch_bounds__(256) void prep_psiT(
    const float* __restrict__ wPsi, ushort_t* __restrict__ psiT)
{
  const int idx = blockIdx.x*256 + threadIdx.x;   // < 512*512
  const int row = idx >> 9, f = idx & 511;
  const int g = row >> 6, ii = row & 63;
  psiT[idx] = (ii < 49) ? f2bf(wPsi[(f*8 + g)*49 + ii]) : (ushort_t)0;
}

// ---------- bf16 MFMA NT GEMM: C[m,n] = sum_k A[m,k]*B[n,k] ----------
// A bf16 [M][lda], B bf16 [N][ldb], 128x128 tile, BK=64, 4 waves.
// mode 0: fp32 store
// mode 1: relu -> bf16 store
// mode 2: split-K fp32 partial (blockIdx.z, kPartLen)
// mode 3: bf16 store + optional rank-1 bias biasRow[m&63]*biasCol[n]
#define LSTR 72
__global__ __launch_bounds__(256, 2) void gemm_bf16_nt(
    const ushort_t* __restrict__ A, const ushort_t* __restrict__ B, void* __restrict__ Cv,
    int M, int N, int K, int lda, int ldb, int ldc,
    int mode, const float* __restrict__ biasRow, const float* __restrict__ biasCol,
    int kPartLen)
{
  __shared__ ushort_t Alds[128*LSTR];
  __shared__ ushort_t Blds[128*LSTR];
  const int tid  = threadIdx.x;
  const int wave = tid >> 6, lane = tid & 63;
  const int wm = wave >> 1, wn = wave & 1;
  const int col = lane & 15, quad = lane >> 4;
  const int m0 = blockIdx.y * 128, n0 = blockIdx.x * 128;
  int kStart = 0, kEnd = K;
  float*    C  = (float*)Cv;
  ushort_t* Cb = (ushort_t*)Cv;
  if (mode == 2) {
    kStart = blockIdx.z * kPartLen;
    kEnd = min(K, kStart + kPartLen);
    C += (size_t)blockIdx.z * (size_t)M * (size_t)ldc;
  }

  f32x4 acc[4][4];
  #pragma unroll
  for (int i = 0; i < 4; ++i)
    #pragma unroll
    for (int j = 0; j < 4; ++j)
      acc[i][j] = (f32x4){0.f,0.f,0.f,0.f};

  for (int k0 = kStart; k0 < kEnd; k0 += 64) {
    #pragma unroll
    for (int r = 0; r < 4; ++r) {
      const int u = tid + 256*r;
      const int mm = u >> 3, kg = u & 7;
      *(uint4*)&Alds[mm*LSTR + kg*8] = *(const uint4*)&A[(size_t)(m0+mm)*lda + k0 + kg*8];
      *(uint4*)&Blds[mm*LSTR + kg*8] = *(const uint4*)&B[(size_t)(n0+mm)*ldb + k0 + kg*8];
    }
    __syncthreads();
    #pragma unroll
    for (int ks = 0; ks < 2; ++ks) {
      bf16x8 af[4], bfr[4];
      #pragma unroll
      for (int t = 0; t < 4; ++t) {
        af[t]  = *(bf16x8*)&Alds[(wm*64 + t*16 + col)*LSTR + ks*32 + quad*8];
        bfr[t] = *(bf16x8*)&Blds[(wn*64 + t*16 + col)*LSTR + ks*32 + quad*8];
      }
      #pragma unroll
      for (int i = 0; i < 4; ++i)
        #pragma unroll
        for (int j = 0; j < 4; ++j)
          acc[i][j] = __builtin_amdgcn_mfma_f32_16x16x32_bf16(af[i], bfr[j], acc[i][j], 0, 0, 0);
    }
    __syncthreads();
  }

  // epilogue: C/D layout col = lane&15, row = quad*4 + reg
  #pragma unroll
  for (int i = 0; i < 4; ++i) {
    const int mBase = m0 + wm*64 + i*16 + quad*4;
    #pragma unroll
    for (int j = 0; j < 4; ++j) {
      const int n = n0 + wn*64 + j*16 + col;
      if (mode == 1) {
        #pragma unroll
        for (int r = 0; r < 4; ++r)
          Cb[(size_t)(mBase+r)*ldc + n] = f2bf(fmaxf(acc[i][j][r], 0.f));
      } else if (mode == 3) {
        #pragma unroll
        for (int r = 0; r < 4; ++r) {
          float v = acc[i][j][r];
          if (biasRow) v += biasRow[(mBase+r) & 63] * biasCol[n];
          Cb[(size_t)(mBase+r)*ldc + n] = f2bf(v);
        }
      } else {
        #pragma unroll
        for (int r = 0; r < 4; ++r)
          C[(size_t)(mBase+r)*ldc + n] = acc[i][j][r];
      }
    }
  }
}

// ---------- gather block-diagonal of CS2 into yPad (incl. zeroing pad cols) ----------
// yPad[(b*8+g)*512 + j] = CS2[(b*64 + l^2 + m)*512 + g*64 + l^2 + u] / sqrt(512)
// where j = soff(l) + u*d + m; j>=455 -> 0.
__global__ __launch_bounds__(256) void gather_y(
    const float* __restrict__ CS2, ushort_t* __restrict__ y)
{
  const int idx = blockIdx.x*256 + threadIdx.x;   // < 1024*512
  const int rowOut = idx >> 9, j = idx & 511;
  const int b = rowOut >> 3, g = rowOut & 7;
  float v = 0.f;
  if (j < SO3D) {
    int l;
    if (j < 1) l = 0; else if (j < 10) l = 1; else if (j < 35) l = 2;
    else if (j < 84) l = 3; else if (j < 165) l = 4; else if (j < 286) l = 5; else l = 6;
    const int so = soff(l), d = 2*l+1;
    const int r = j - so;
    const int u = r / d, m = r - u*d;
    v = CS2[(size_t)(b*64 + l*l + m)*512 + g*64 + l*l + u] * 0.044194173824159216f;
  }
  y[idx] = f2bf(v);
}

// ---------- final so3 conv: 8-partial sum + per-l contraction + fp32 store ----------
__global__ __launch_bounds__(512) void so3_final(
    const float* __restrict__ zpart, const float* __restrict__ psi2,
    float* __restrict__ out)
{
  __shared__ float Zs[8*SO3D];
  __shared__ float P2s[8*SO3D];
  const int b = blockIdx.x, tid = threadIdx.x;
  for (int idx = tid; idx < 8*SO3D; idx += 512) {
    const int f = idx / SO3D, i = idx - f*SO3D;
    float s = 0.f;
    #pragma unroll
    for (int p = 0; p < 8; ++p)
      s += zpart[((size_t)p*1024 + (size_t)b*FHID + f)*512 + i];
    Zs[idx] = s;
    P2s[idx] = psi2[idx];
  }
  __syncthreads();
  if (tid < SO3D) {
    const int i = tid;
    int l;
    if (i < 1) l = 0; else if (i < 10) l = 1; else if (i < 35) l = 2;
    else if (i < 84) l = 3; else if (i < 165) l = 4; else if (i < 286) l = 5; else l = 6;
    const int so = soff(l), d = 2*l+1;
    const int r = i - so;
    const int v = r / d, m = r - v*d;
    float acc = 0.f;
    for (int f = 0; f < 8; ++f)
      for (int u = 0; u < d; ++u)
        acc = fmaf(Zs[f*SO3D + so + u*d + m], P2s[f*SO3D + so + u*d + v], acc);
    const float scale = rsqrtf(8.0f * (float)d);
    out[(size_t)b*SO3D + i] = acc * scale;
  }
}

extern "C" void kernel_launch(void* const* d_in, const int* in_sizes, int n_in,
                              void* d_out, int out_size, void* d_ws, size_t ws_size,
                              hipStream_t stream) {
  const float* fmap    = (const float*)d_in[0];
  const float* conv_w  = (const float*)d_in[1];
  const float* conv_b  = (const float*)d_in[2];
  const float* proj_w  = (const float*)d_in[3];
  const float* proj_Y  = (const float*)d_in[4];
  const float* fs_w    = (const float*)d_in[5];
  const float* fs_Y    = (const float*)d_in[6];
  const float* act_to  = (const float*)d_in[7];
  const float* act_from= (const float*)d_in[8];
  const float* so3_w   = (const float*)d_in[9];
  const float* so3_D   = (const float*)d_in[10];
  float* out           = (float*)d_out;

  // byte-offset workspace layout (aliasing by lifetime), total ~54.8 MB
  char* wsb = (char*)d_ws;
  float*    wP       = (float*)(wsb + 0);           // 49x49 fp32
  float*    wSumP    = (float*)(wsb + 9728);        // 64 fp32
  float*    wPsi     = (float*)(wsb + 9984);        // 4096x49 fp32
  float*    wPsi2    = (float*)(wsb + 812800);      // 8x455 fp32
  ushort_t* cwB      = (ushort_t*)(wsb + 827392);   // 512x2048 bf16
  ushort_t* actToT   = (ushort_t*)(wsb + 2924544);  // 4096x512 bf16
  ushort_t* actFromT = (ushort_t*)(wsb + 7118848);  // 512x4096 bf16
  ushort_t* yPad     = (ushort_t*)(wsb + 11313152); // 1024x512 bf16
  ushort_t* psiT     = (ushort_t*)(wsb + 12361728); // 512x512 bf16
  ushort_t* x3BT     = (ushort_t*)(wsb + 12886016); // 8192x512 bf16 (dead after s2 gemm)
  ushort_t* gBuf     = (ushort_t*)(wsb + 12886016); // 1024x4096 bf16, aliases dead x3BT
  ushort_t* fmapPT   = (ushort_t*)(wsb + 21274624); // 8192x2048 bf16 (dead after conv gemm)
  float*    CS2      = (float*)(wsb + 21274624);    // 8192x512 fp32, aliases dead fmapPT
  float*    zPart    = (float*)(wsb + 21274624);    // 8x1024x512 fp32, aliases dead CS2

  const float is192 = 0.07216878364870323f;  // 1/sqrt(192)

  // prep
  gemm_nn<<<dim3(1,1), 256, 0, stream>>>(proj_w, proj_Y, wP, 49,49,192, 192,49,49, is192);
  gemm_nn<<<dim3(1,64), 256, 0, stream>>>(fs_w, fs_Y, wPsi, 4096,49,192, 192,49,49, is192);
  gemm_nn<<<dim3(8,1), 256, 0, stream>>>(so3_w, so3_D, wPsi2, 8,455,192, 192,455,455, is192);
  cvt_bf16<<<dim3(1024), 256, 0, stream>>>(conv_w, cwB, 512*2048);
  transpose_cvt<<<dim3(128,16), 256, 0, stream>>>(act_to, 455, 4000, actToT, 512, 4096);
  transpose_cvt<<<dim3(16,128), 256, 0, stream>>>(act_from, 4000, 455, actFromT, 4096, 512);
  prep_fmapPT<<<dim3(32,128), 256, 0, stream>>>(fmap, wP, wSumP, fmapPT);
  prep_psiT<<<dim3(1024), 256, 0, stream>>>(wPsi, psiT);

  // x3BT[(b,i)][f] = bf16( fmapPT @ cwB^T + sumP[i]*conv_b[f] )   (M=8192, N=512, K=2048)
  gemm_bf16_nt<<<dim3(4,64), 256, 0, stream>>>(fmapPT, cwB, x3BT,
      8192, 512, 2048, 2048, 2048, 512, 3, wSumP, conv_b, 0);
  // CS2[(b,i)][(g,itil)] = x3BT @ psiT^T   (M=8192, N=512, K=512) — contains all s2->so3 values
  gemm_bf16_nt<<<dim3(4,64), 256, 0, stream>>>(x3BT, psiT, CS2,
      8192, 512, 512, 512, 512, 512, 0, nullptr, nullptr, 0);
  // yPad = block-diagonal gather of CS2 (+ 1/sqrt(512), + pad zeros)
  gather_y<<<dim3(2048), 256, 0, stream>>>(CS2, yPad);
  // g = relu(yPad @ actToT^T) bf16   (M=1024, N=4096, K=512)
  gemm_bf16_nt<<<dim3(32,8), 256, 0, stream>>>(yPad, actToT, gBuf,
      1024, 4096, 512, 512, 512, 4096, 1, nullptr, nullptr, 0);
  // zPart = g @ actFromT^T, split-K=8   (M=1024, N=512, K=4096)
  gemm_bf16_nt<<<dim3(4,8,8), 256, 0, stream>>>(gBuf, actFromT, zPart,
      1024, 512, 4096, 4096, 4096, 512, 2, nullptr, nullptr, 512);
  // final contraction + fp32 store
  so3_final<<<dim3(128), 512, 0, stream>>>(zPart, wPsi2, out);
}

// Round 7
// 329.888 us; speedup vs baseline: 2.4522x; 1.0880x over previous
//
#include <hip/hip_runtime.h>
#include <hip/hip_bf16.h>

#define NB    128
#define CENC  2048
#define FIN   512
#define FHID  8
#define S2D   49
#define SO3D  455
#define HW    49

typedef unsigned short ushort_t;
typedef __bf16 bf16x8 __attribute__((ext_vector_type(8)));
typedef float  f32x4  __attribute__((ext_vector_type(4)));

__device__ __forceinline__ int soff(int l) { return l*(4*l*l-1)/3; }  // sum_{l'<l}(2l'+1)^2

__device__ __forceinline__ ushort_t f2bf(float x) {
  __hip_bfloat16 h = __float2bfloat16(x);
  return *reinterpret_cast<ushort_t*>(&h);
}
__device__ __forceinline__ float bf2f(ushort_t u) {
  __hip_bfloat16 h = *reinterpret_cast<__hip_bfloat16*>(&u);
  return __bfloat162float(h);
}

// ---------- small fp32 GEMM (tiny preps only): C = alpha * A@B ----------
__global__ __launch_bounds__(256) void gemm_nn(
    const float* __restrict__ A, const float* __restrict__ B, float* __restrict__ C,
    int M, int N, int K, int lda, int ldb, int ldc, float alpha)
{
  __shared__ float As[32*68];
  __shared__ float Bs[32*68];
  const int tid = threadIdx.x;
  const int tx = tid & 15, ty = tid >> 4;
  const int n0 = blockIdx.x * 64, m0 = blockIdx.y * 64;
  float acc[4][4] = {};
  for (int k0 = 0; k0 < K; k0 += 32) {
    {
      const int kk = tid & 31, mmB = tid >> 5;
      #pragma unroll
      for (int j = 0; j < 8; ++j) {
        const int mm = mmB + 8*j;
        const int m = m0 + mm, k = k0 + kk;
        As[kk*68 + mm] = (m < M && k < K) ? A[(size_t)m*lda + k] : 0.f;
      }
    }
    {
      const int nn = tid & 63, kkB = tid >> 6;
      #pragma unroll
      for (int j = 0; j < 8; ++j) {
        const int kk = kkB + 4*j;
        const int n = n0 + nn, k = k0 + kk;
        Bs[kk*68 + nn] = (n < N && k < K) ? B[(size_t)k*ldb + n] : 0.f;
      }
    }
    __syncthreads();
    #pragma unroll
    for (int kk = 0; kk < 32; ++kk) {
      const float4 a4 = *(const float4*)&As[kk*68 + ty*4];
      const float4 b4 = *(const float4*)&Bs[kk*68 + tx*4];
      const float av[4] = {a4.x,a4.y,a4.z,a4.w};
      const float bv[4] = {b4.x,b4.y,b4.z,b4.w};
      #pragma unroll
      for (int i = 0; i < 4; ++i)
        #pragma unroll
        for (int j = 0; j < 4; ++j)
          acc[i][j] = fmaf(av[i], bv[j], acc[i][j]);
    }
    __syncthreads();
  }
  #pragma unroll
  for (int i = 0; i < 4; ++i) {
    const int m = m0 + ty*4 + i;
    if (m >= M) continue;
    #pragma unroll
    for (int j = 0; j < 4; ++j) {
      const int n = n0 + tx*4 + j;
      if (n >= N) continue;
      C[(size_t)m*ldc + n] = acc[i][j] * alpha;
    }
  }
}

// ---------- fp32 -> bf16 elementwise ----------
__global__ void cvt_bf16(const float* __restrict__ in, ushort_t* __restrict__ out, int n4) {
  int i = (blockIdx.x*256 + threadIdx.x)*4;
  if (i < n4) {
    float4 v = *(const float4*)&in[i];
    out[i+0] = f2bf(v.x); out[i+1] = f2bf(v.y);
    out[i+2] = f2bf(v.z); out[i+3] = f2bf(v.w);
  }
}

// ---------- transpose + cvt + pad: in fp32 [R][C] -> out bf16 [Cp][Rp] (zeros outside) ----------
__global__ __launch_bounds__(256) void transpose_cvt(
    const float* __restrict__ in, int R, int C,
    ushort_t* __restrict__ out, int Rp, int Cp)
{
  __shared__ float t[32][33];
  const int c0 = blockIdx.x*32, r0 = blockIdx.y*32;
  const int tx = threadIdx.x & 31, ty = threadIdx.x >> 5;
  #pragma unroll
  for (int j = 0; j < 4; ++j) {
    const int r = r0 + ty + j*8, c = c0 + tx;
    t[ty + j*8][tx] = (r < R && c < C) ? in[(size_t)r*C + c] : 0.f;
  }
  __syncthreads();
  #pragma unroll
  for (int j = 0; j < 4; ++j) {
    const int c = c0 + ty + j*8, r = r0 + tx;
    if (c < Cp && r < Rp) out[(size_t)c*Rp + r] = f2bf(t[tx][ty + j*8]);
  }
}

// ---------- fmapPT[b*49+i][c] = bf16( sum_hw fmap[b,c,hw] * P[hw,i] ), packed rows ----------
// (R4 lesson: no dynamically-indexed per-thread arrays -> scratch demotion.)
__global__ __launch_bounds__(256) void prep_fmapPT(
    const float* __restrict__ fmap, const float* __restrict__ P,
    float* __restrict__ sumP, ushort_t* __restrict__ out)
{
  __shared__ float Fs[64*49];   // [c_local][hw], flat coalesced copy
  __shared__ float Ps[49*64];   // [hw][i(64)], zeros for i>=49
  const int tid = threadIdx.x;
  const int cc = blockIdx.x, b = blockIdx.y;
  const int c0 = cc*64;

  const float* fsrc = fmap + ((size_t)b*CENC + c0)*HW;   // 3136 floats, contiguous
  for (int idx = tid; idx < 784; idx += 256)
    *(float4*)&Fs[idx*4] = *(const float4*)&fsrc[idx*4];
  for (int idx = tid; idx < 49*64; idx += 256) {
    const int h = idx >> 6, i = idx & 63;
    Ps[idx] = (i < 49) ? P[h*49 + i] : 0.f;
  }
  __syncthreads();

  if (b == 0 && cc == 0 && tid < 64) {
    float s = 0.f;
    if (tid < 49) for (int hw = 0; hw < 49; ++hw) s += P[hw*49 + tid];
    sumP[tid] = (tid < 49) ? s : 0.f;
  }

  const int cl = tid & 63, g = tid >> 6;
  float acc[16];
  #pragma unroll
  for (int ii = 0; ii < 16; ++ii) acc[ii] = 0.f;

  #pragma unroll 7
  for (int h = 0; h < 49; ++h) {
    const float fv = Fs[cl*49 + h];
    const float4 p0 = *(const float4*)&Ps[h*64 + g*16 + 0];
    const float4 p1 = *(const float4*)&Ps[h*64 + g*16 + 4];
    const float4 p2 = *(const float4*)&Ps[h*64 + g*16 + 8];
    const float4 p3 = *(const float4*)&Ps[h*64 + g*16 + 12];
    acc[ 0] = fmaf(fv, p0.x, acc[ 0]);
    acc[ 1] = fmaf(fv, p0.y, acc[ 1]);
    acc[ 2] = fmaf(fv, p0.z, acc[ 2]);
    acc[ 3] = fmaf(fv, p0.w, acc[ 3]);
    acc[ 4] = fmaf(fv, p1.x, acc[ 4]);
    acc[ 5] = fmaf(fv, p1.y, acc[ 5]);
    acc[ 6] = fmaf(fv, p1.z, acc[ 6]);
    acc[ 7] = fmaf(fv, p1.w, acc[ 7]);
    acc[ 8] = fmaf(fv, p2.x, acc[ 8]);
    acc[ 9] = fmaf(fv, p2.y, acc[ 9]);
    acc[10] = fmaf(fv, p2.z, acc[10]);
    acc[11] = fmaf(fv, p2.w, acc[11]);
    acc[12] = fmaf(fv, p3.x, acc[12]);
    acc[13] = fmaf(fv, p3.y, acc[13]);
    acc[14] = fmaf(fv, p3.z, acc[14]);
    acc[15] = fmaf(fv, p3.w, acc[15]);
  }

  ushort_t* op = out + (size_t)b*49*CENC + c0 + cl;
  #pragma unroll
  for (int ii = 0; ii < 16; ++ii) {
    const int i = g*16 + ii;
    if (i < 49) op[(size_t)i*CENC] = f2bf(acc[ii]);
  }
}

// ---------- psiT[(g*64+ii)][f] = bf16( wPsiP[(f*8+g)*128 + ii] * 1/sqrt(192) ), ii>=49 -> 0 ----------
__global__ __launch_bounds__(256) void prep_psiT(
    const float* __restrict__ wPsiP, ushort_t* __restrict__ psiT)
{
  const int idx = blockIdx.x*256 + threadIdx.x;   // < 512*512
  const int row = idx >> 9, f = idx & 511;
  const int g = row >> 6, ii = row & 63;
  const float is192 = 0.07216878364870323f;
  psiT[idx] = (ii < 49) ? f2bf(wPsiP[(size_t)(f*8 + g)*128 + ii] * is192) : (ushort_t)0;
}

// ---------- bpsi[gi] = sum_f conv_b[f] * psiT[gi][f]  (wave per gi, coalesced) ----------
__global__ __launch_bounds__(256) void bpsi_kernel(
    const ushort_t* __restrict__ psiT, const float* __restrict__ conv_b,
    float* __restrict__ bpsi)
{
  const int w = threadIdx.x >> 6, lane = threadIdx.x & 63;
  const int gi = blockIdx.x*4 + w;
  float s = 0.f;
  #pragma unroll
  for (int s8 = 0; s8 < 8; ++s8) {
    const int f = s8*64 + lane;
    s += conv_b[f] * bf2f(psiT[(size_t)gi*512 + f]);
  }
  #pragma unroll
  for (int off = 32; off; off >>= 1) s += __shfl_down(s, off);
  if (lane == 0) bpsi[gi] = s;
}

// ---------- bf16 MFMA NT GEMM, 8 waves (512 thr): C[m,n] = sum_k A[m,k]*B[n,k] ----------
// 128x128 tile, BK=64, wave-tile 32x64 (wave grid 4x2). M,N multiples of 128; K mult of 64.
// mode 0: fp32 store | mode 1: relu->bf16 | mode 2: split-K fp32 partial | mode 3: bf16 store
#define LSTR 72
__global__ __launch_bounds__(512) void gemm8_nt(
    const ushort_t* __restrict__ A, const ushort_t* __restrict__ B, void* __restrict__ Cv,
    int M, int N, int K, int lda, int ldb, int ldc,
    int mode, int kPartLen)
{
  __shared__ ushort_t Alds[128*LSTR];
  __shared__ ushort_t Blds[128*LSTR];
  const int tid  = threadIdx.x;
  const int wave = tid >> 6, lane = tid & 63;
  const int wm = wave >> 1, wn = wave & 1;          // 4 x 2 wave grid
  const int col = lane & 15, quad = lane >> 4;
  const int m0 = blockIdx.y * 128, n0 = blockIdx.x * 128;
  int kStart = 0, kEnd = K;
  float*    C  = (float*)Cv;
  ushort_t* Cb = (ushort_t*)Cv;
  if (mode == 2) {
    kStart = blockIdx.z * kPartLen;
    kEnd = min(K, kStart + kPartLen);
    C += (size_t)blockIdx.z * (size_t)M * (size_t)ldc;
  }

  f32x4 acc[2][4];
  #pragma unroll
  for (int i = 0; i < 2; ++i)
    #pragma unroll
    for (int j = 0; j < 4; ++j)
      acc[i][j] = (f32x4){0.f,0.f,0.f,0.f};

  for (int k0 = kStart; k0 < kEnd; k0 += 64) {
    #pragma unroll
    for (int r = 0; r < 2; ++r) {
      const int u = tid + 512*r;
      const int mm = u >> 3, kg = u & 7;
      *(uint4*)&Alds[mm*LSTR + kg*8] = *(const uint4*)&A[(size_t)(m0+mm)*lda + k0 + kg*8];
      *(uint4*)&Blds[mm*LSTR + kg*8] = *(const uint4*)&B[(size_t)(n0+mm)*ldb + k0 + kg*8];
    }
    __syncthreads();
    #pragma unroll
    for (int ks = 0; ks < 2; ++ks) {
      bf16x8 af[2], bfr[4];
      #pragma unroll
      for (int t = 0; t < 2; ++t)
        af[t]  = *(bf16x8*)&Alds[(wm*32 + t*16 + col)*LSTR + ks*32 + quad*8];
      #pragma unroll
      for (int t = 0; t < 4; ++t)
        bfr[t] = *(bf16x8*)&Blds[(wn*64 + t*16 + col)*LSTR + ks*32 + quad*8];
      #pragma unroll
      for (int i = 0; i < 2; ++i)
        #pragma unroll
        for (int j = 0; j < 4; ++j)
          acc[i][j] = __builtin_amdgcn_mfma_f32_16x16x32_bf16(af[i], bfr[j], acc[i][j], 0, 0, 0);
    }
    __syncthreads();
  }

  // epilogue: C/D layout col = lane&15, row = quad*4 + reg
  #pragma unroll
  for (int i = 0; i < 2; ++i) {
    const int mBase = m0 + wm*32 + i*16 + quad*4;
    #pragma unroll
    for (int j = 0; j < 4; ++j) {
      const int n = n0 + wn*64 + j*16 + col;
      if (mode == 1) {
        #pragma unroll
        for (int r = 0; r < 4; ++r)
          Cb[(size_t)(mBase+r)*ldc + n] = f2bf(fmaxf(acc[i][j][r], 0.f));
      } else if (mode == 3) {
        #pragma unroll
        for (int r = 0; r < 4; ++r)
          Cb[(size_t)(mBase+r)*ldc + n] = f2bf(acc[i][j][r]);
      } else {
        #pragma unroll
        for (int r = 0; r < 4; ++r)
          C[(size_t)(mBase+r)*ldc + n] = acc[i][j][r];
      }
    }
  }
}

// ---------- gather block-diagonal of CS2 into yPad (+rank-1 bias, +1/sqrt(512), pad zeros) ----------
// yPad[(b*8+g)*512 + j], j=soff(l)+u*d+m:
//   v = CS2[(b*49 + l^2+m)*512 + g*64 + l^2+u] + sumP[l^2+m]*bpsi[g*64+l^2+u]
__global__ __launch_bounds__(256) void gather_y(
    const float* __restrict__ CS2, const float* __restrict__ sumP,
    const float* __restrict__ bpsi, ushort_t* __restrict__ y)
{
  const int idx = blockIdx.x*256 + threadIdx.x;   // < 1024*512
  const int rowOut = idx >> 9, j = idx & 511;
  const int b = rowOut >> 3, g = rowOut & 7;
  float v = 0.f;
  if (j < SO3D) {
    int l;
    if (j < 1) l = 0; else if (j < 10) l = 1; else if (j < 35) l = 2;
    else if (j < 84) l = 3; else if (j < 165) l = 4; else if (j < 286) l = 5; else l = 6;
    const int so = soff(l), d = 2*l+1;
    const int r = j - so;
    const int u = r / d, m = r - u*d;
    const int i = l*l + m, gi = g*64 + l*l + u;
    v = (CS2[(size_t)(b*49 + i)*512 + gi] + sumP[i]*bpsi[gi]) * 0.044194173824159216f;
  }
  y[idx] = f2bf(v);
}

// ---------- final so3 conv: 8-partial sum + per-l contraction + fp32 store ----------
__global__ __launch_bounds__(512) void so3_final(
    const float* __restrict__ zpart, const float* __restrict__ psi2,
    float* __restrict__ out)
{
  __shared__ float Zs[8*SO3D];
  __shared__ float P2s[8*SO3D];
  const int b = blockIdx.x, tid = threadIdx.x;
  for (int idx = tid; idx < 8*SO3D; idx += 512) {
    const int f = idx / SO3D, i = idx - f*SO3D;
    float s = 0.f;
    #pragma unroll
    for (int p = 0; p < 8; ++p)
      s += zpart[((size_t)p*1024 + (size_t)b*FHID + f)*512 + i];
    Zs[idx] = s;
    P2s[idx] = psi2[idx];
  }
  __syncthreads();
  if (tid < SO3D) {
    const int i = tid;
    int l;
    if (i < 1) l = 0; else if (i < 10) l = 1; else if (i < 35) l = 2;
    else if (i < 84) l = 3; else if (i < 165) l = 4; else if (i < 286) l = 5; else l = 6;
    const int so = soff(l), d = 2*l+1;
    const int r = i - so;
    const int v = r / d, m = r - v*d;
    float acc = 0.f;
    for (int f = 0; f < 8; ++f)
      for (int u = 0; u < d; ++u)
        acc = fmaf(Zs[f*SO3D + so + u*d + m], P2s[f*SO3D + so + u*d + v], acc);
    const float scale = rsqrtf(8.0f * (float)d);
    out[(size_t)b*SO3D + i] = acc * scale;
  }
}

extern "C" void kernel_launch(void* const* d_in, const int* in_sizes, int n_in,
                              void* d_out, int out_size, void* d_ws, size_t ws_size,
                              hipStream_t stream) {
  const float* fmap    = (const float*)d_in[0];
  const float* conv_w  = (const float*)d_in[1];
  const float* conv_b  = (const float*)d_in[2];
  const float* proj_w  = (const float*)d_in[3];
  const float* proj_Y  = (const float*)d_in[4];
  const float* fs_w    = (const float*)d_in[5];
  const float* fs_Y    = (const float*)d_in[6];
  const float* act_to  = (const float*)d_in[7];
  const float* act_from= (const float*)d_in[8];
  const float* so3_w   = (const float*)d_in[9];
  const float* so3_D   = (const float*)d_in[10];
  float* out           = (float*)d_out;

  // workspace (bytes), lifetime-packed; max 50.6 MB
  char* wsb = (char*)d_ws;
  float*    wP       = (float*)(wsb + 0);           // 49x49 fp32
  float*    wSumP    = (float*)(wsb + 9728);        // 64 fp32
  float*    wPsi2    = (float*)(wsb + 9984);        // 8x455 fp32 -> 24544, pad 24576
  ushort_t* actToT   = (ushort_t*)(wsb + 24576);    // 4096x512 bf16 -> 4218880
  ushort_t* actFromT = (ushort_t*)(wsb + 4218880);  // 512x4096 bf16 -> 8413184
  ushort_t* yPad     = (ushort_t*)(wsb + 8413184);  // 1024x512 bf16 -> 9461760
  ushort_t* psiT     = (ushort_t*)(wsb + 9461760);  // 512x512 bf16 -> 9986048
  float*    bpsi     = (float*)(wsb + 9986048);     // 512 fp32 -> 9988096
  ushort_t* W2T      = (ushort_t*)(wsb + 9988096);  // 512x2048 bf16 -> 12085248
  ushort_t* fmapPT   = (ushort_t*)(wsb + 12085248); // 6272x2048 bf16 -> 37775360 (dead after CS2 gemm)
  // X-region (all dead before CS2 gemm), aliased by CS2:
  float*    wPsiP    = (float*)(wsb + 37775360);    // 4096x128 fp32 -> 39872512
  ushort_t* fswB     = (ushort_t*)(wsb + 39872512); // 4096x192 bf16 -> 41445376
  ushort_t* fsYT     = (ushort_t*)(wsb + 41445376); // 128x192 bf16  -> 41494528
  ushort_t* cwT      = (ushort_t*)(wsb + 41494528); // 2048x512 bf16 -> 43591680
  float*    CS2      = (float*)(wsb + 37775360);    // 6272x512 fp32 -> 50620416 (aliases X)
  // alias into dead fmapPT region:
  ushort_t* gBuf     = (ushort_t*)(wsb + 12085248); // 1024x4096 bf16 -> 20473856
  float*    zPart    = (float*)(wsb + 20473856);    // 8x1024x512 fp32 -> 37251072

  const float is192 = 0.07216878364870323f;  // 1/sqrt(192)

  // --- prep ---
  gemm_nn<<<dim3(1,1), 256, 0, stream>>>(proj_w, proj_Y, wP, 49,49,192, 192,49,49, is192);
  gemm_nn<<<dim3(8,1), 256, 0, stream>>>(so3_w, so3_D, wPsi2, 8,455,192, 192,455,455, is192);
  cvt_bf16<<<dim3(768), 256, 0, stream>>>(fs_w, fswB, 4096*192);
  transpose_cvt<<<dim3(4,6),   256, 0, stream>>>(fs_Y, 192, 49, fsYT, 192, 128);
  transpose_cvt<<<dim3(128,16),256, 0, stream>>>(act_to, 455, 4000, actToT, 512, 4096);
  transpose_cvt<<<dim3(16,128),256, 0, stream>>>(act_from, 4000, 455, actFromT, 4096, 512);
  transpose_cvt<<<dim3(64,16), 256, 0, stream>>>(conv_w, 512, 2048, cwT, 512, 2048);
  prep_fmapPT<<<dim3(32,128), 256, 0, stream>>>(fmap, wP, wSumP, fmapPT);

  // wPsiP[(f,g)][ii(128)] = fs_w @ fs_Y   (M=4096, N=128, K=192), scale folded into prep_psiT
  gemm8_nt<<<dim3(1,32), 512, 0, stream>>>(fswB, fsYT, wPsiP,
      4096, 128, 192, 192, 192, 128, 0, 0);
  prep_psiT<<<dim3(1024), 256, 0, stream>>>(wPsiP, psiT);
  bpsi_kernel<<<dim3(128), 256, 0, stream>>>(psiT, conv_b, bpsi);

  // W2T[gi][c] = psiT @ cwT^T   (M=512, N=2048, K=512), bf16 out
  gemm8_nt<<<dim3(16,4), 512, 0, stream>>>(psiT, cwT, W2T,
      512, 2048, 512, 512, 512, 2048, 3, 0);
  // CS2[(b,i)][gi] = fmapPT @ W2T^T   (M=6272, N=512, K=2048), fp32 out — fused conv+s2
  gemm8_nt<<<dim3(4,49), 512, 0, stream>>>(fmapPT, W2T, CS2,
      6272, 512, 2048, 2048, 2048, 512, 0, 0);
  // yPad = block-diag gather + rank-1 bias + 1/sqrt(512)
  gather_y<<<dim3(2048), 256, 0, stream>>>(CS2, wSumP, bpsi, yPad);
  // g = relu(yPad @ actToT^T) bf16   (M=1024, N=4096, K=512)
  gemm8_nt<<<dim3(32,8), 512, 0, stream>>>(yPad, actToT, gBuf,
      1024, 4096, 512, 512, 512, 4096, 1, 0);
  // zPart = gBuf @ actFromT^T, split-K=8   (M=1024, N=512, K=4096)
  gemm8_nt<<<dim3(4,8,8), 512, 0, stream>>>(gBuf, actFromT, zPart,
      1024, 512, 4096, 4096, 4096, 512, 2, 512);
  // final contraction + fp32 store
  so3_final<<<dim3(128), 512, 0, stream>>>(zPart, wPsi2, out);
}

// Round 8
// 311.413 us; speedup vs baseline: 2.5977x; 1.0593x over previous
//
#include <hip/hip_runtime.h>
#include <hip/hip_bf16.h>

#define NB    128
#define CENC  2048
#define FIN   512
#define FHID  8
#define S2D   49
#define SO3D  455
#define HW    49

typedef unsigned short ushort_t;
typedef __bf16 bf16x8 __attribute__((ext_vector_type(8)));
typedef float  f32x4  __attribute__((ext_vector_type(4)));

__device__ __forceinline__ int soff(int l) { return l*(4*l*l-1)/3; }  // sum_{l'<l}(2l'+1)^2

__device__ __forceinline__ ushort_t f2bf(float x) {
  __hip_bfloat16 h = __float2bfloat16(x);
  return *reinterpret_cast<ushort_t*>(&h);
}
__device__ __forceinline__ float bf2f(ushort_t u) {
  __hip_bfloat16 h = *reinterpret_cast<__hip_bfloat16*>(&u);
  return __bfloat162float(h);
}

// ---------- small fp32 GEMM (tiny preps only): C = alpha * A@B ----------
__global__ __launch_bounds__(256) void gemm_nn(
    const float* __restrict__ A, const float* __restrict__ B, float* __restrict__ C,
    int M, int N, int K, int lda, int ldb, int ldc, float alpha)
{
  __shared__ float As[32*68];
  __shared__ float Bs[32*68];
  const int tid = threadIdx.x;
  const int tx = tid & 15, ty = tid >> 4;
  const int n0 = blockIdx.x * 64, m0 = blockIdx.y * 64;
  float acc[4][4] = {};
  for (int k0 = 0; k0 < K; k0 += 32) {
    {
      const int kk = tid & 31, mmB = tid >> 5;
      #pragma unroll
      for (int j = 0; j < 8; ++j) {
        const int mm = mmB + 8*j;
        const int m = m0 + mm, k = k0 + kk;
        As[kk*68 + mm] = (m < M && k < K) ? A[(size_t)m*lda + k] : 0.f;
      }
    }
    {
      const int nn = tid & 63, kkB = tid >> 6;
      #pragma unroll
      for (int j = 0; j < 8; ++j) {
        const int kk = kkB + 4*j;
        const int n = n0 + nn, k = k0 + kk;
        Bs[kk*68 + nn] = (n < N && k < K) ? B[(size_t)k*ldb + n] : 0.f;
      }
    }
    __syncthreads();
    #pragma unroll
    for (int kk = 0; kk < 32; ++kk) {
      const float4 a4 = *(const float4*)&As[kk*68 + ty*4];
      const float4 b4 = *(const float4*)&Bs[kk*68 + tx*4];
      const float av[4] = {a4.x,a4.y,a4.z,a4.w};
      const float bv[4] = {b4.x,b4.y,b4.z,b4.w};
      #pragma unroll
      for (int i = 0; i < 4; ++i)
        #pragma unroll
        for (int j = 0; j < 4; ++j)
          acc[i][j] = fmaf(av[i], bv[j], acc[i][j]);
    }
    __syncthreads();
  }
  #pragma unroll
  for (int i = 0; i < 4; ++i) {
    const int m = m0 + ty*4 + i;
    if (m >= M) continue;
    #pragma unroll
    for (int j = 0; j < 4; ++j) {
      const int n = n0 + tx*4 + j;
      if (n >= N) continue;
      C[(size_t)m*ldc + n] = acc[i][j] * alpha;
    }
  }
}

// ---------- fp32 -> bf16 elementwise ----------
__global__ void cvt_bf16(const float* __restrict__ in, ushort_t* __restrict__ out, int n4) {
  int i = (blockIdx.x*256 + threadIdx.x)*4;
  if (i < n4) {
    float4 v = *(const float4*)&in[i];
    out[i+0] = f2bf(v.x); out[i+1] = f2bf(v.y);
    out[i+2] = f2bf(v.z); out[i+3] = f2bf(v.w);
  }
}

// ---------- transpose + cvt + pad: in fp32 [R][C] -> out bf16 [Cp][Rp] (zeros outside) ----------
__global__ __launch_bounds__(256) void transpose_cvt(
    const float* __restrict__ in, int R, int C,
    ushort_t* __restrict__ out, int Rp, int Cp)
{
  __shared__ float t[32][33];
  const int c0 = blockIdx.x*32, r0 = blockIdx.y*32;
  const int tx = threadIdx.x & 31, ty = threadIdx.x >> 5;
  #pragma unroll
  for (int j = 0; j < 4; ++j) {
    const int r = r0 + ty + j*8, c = c0 + tx;
    t[ty + j*8][tx] = (r < R && c < C) ? in[(size_t)r*C + c] : 0.f;
  }
  __syncthreads();
  #pragma unroll
  for (int j = 0; j < 4; ++j) {
    const int c = c0 + ty + j*8, r = r0 + tx;
    if (c < Cp && r < Rp) out[(size_t)c*Rp + r] = f2bf(t[tx][ty + j*8]);
  }
}

// ---------- fmapT[(b*49+h)][c] = bf16(fmap[b][c][h]) — pure transpose+cvt ----------
// R7 lesson: the P-projection belonged AFTER the big GEMM; this is now memory-bound only.
// fmap[b][c0:c0+64][0:49] is a flat contiguous 3136-float range -> float4 copy to LDS.
// grid (CENC/64=32, NB), block 256.
__global__ __launch_bounds__(256) void transpose_fmap(
    const float* __restrict__ fmap, ushort_t* __restrict__ out)
{
  __shared__ float Fs[64*49];   // [c_local][h]
  const int tid = threadIdx.x;
  const int cc = blockIdx.x, b = blockIdx.y;
  const int c0 = cc*64;
  const float* fsrc = fmap + ((size_t)b*CENC + c0)*HW;
  for (int idx = tid; idx < 784; idx += 256)
    *(float4*)&Fs[idx*4] = *(const float4*)&fsrc[idx*4];
  __syncthreads();
  // write: consecutive lanes -> consecutive c (coalesced 128B bf16 rows);
  // LDS read stride 49 (2-way bank alias, free)
  for (int idx = tid; idx < 3136; idx += 256) {
    const int h = idx >> 6, cl = idx & 63;
    out[(size_t)(b*49 + h)*CENC + c0 + cl] = f2bf(Fs[cl*49 + h]);
  }
}

// ---------- sumP[i] = sum_h P[h][i] (P already has 1/sqrt(192) folded), i<49 ----------
__global__ void sumP_kernel(const float* __restrict__ P, float* __restrict__ sumP) {
  const int i = threadIdx.x;
  if (i < 64) {
    float s = 0.f;
    if (i < 49) for (int h = 0; h < 49; ++h) s += P[h*49 + i];
    sumP[i] = (i < 49) ? s : 0.f;
  }
}

// ---------- psiT[(g*64+ii)][f] = bf16( wPsiP[(f*8+g)*128 + ii] * 1/sqrt(192) ), ii>=49 -> 0 ----------
__global__ __launch_bounds__(256) void prep_psiT(
    const float* __restrict__ wPsiP, ushort_t* __restrict__ psiT)
{
  const int idx = blockIdx.x*256 + threadIdx.x;   // < 512*512
  const int row = idx >> 9, f = idx & 511;
  const int g = row >> 6, ii = row & 63;
  const float is192 = 0.07216878364870323f;
  psiT[idx] = (ii < 49) ? f2bf(wPsiP[(size_t)(f*8 + g)*128 + ii] * is192) : (ushort_t)0;
}

// ---------- bpsi[gi] = sum_f conv_b[f] * psiT[gi][f]  (wave per gi, coalesced) ----------
__global__ __launch_bounds__(256) void bpsi_kernel(
    const ushort_t* __restrict__ psiT, const float* __restrict__ conv_b,
    float* __restrict__ bpsi)
{
  const int w = threadIdx.x >> 6, lane = threadIdx.x & 63;
  const int gi = blockIdx.x*4 + w;
  float s = 0.f;
  #pragma unroll
  for (int s8 = 0; s8 < 8; ++s8) {
    const int f = s8*64 + lane;
    s += conv_b[f] * bf2f(psiT[(size_t)gi*512 + f]);
  }
  #pragma unroll
  for (int off = 32; off; off >>= 1) s += __shfl_down(s, off);
  if (lane == 0) bpsi[gi] = s;
}

// ---------- bf16 MFMA NT GEMM, 8 waves (512 thr): C[m,n] = sum_k A[m,k]*B[n,k] ----------
// 128x128 tile, BK=64, wave-tile 32x64 (wave grid 4x2). M,N multiples of 128; K mult of 64.
// mode 0: fp32 store | mode 1: relu->bf16 | mode 2: split-K fp32 partial | mode 3: bf16 store
#define LSTR 72
__global__ __launch_bounds__(512) void gemm8_nt(
    const ushort_t* __restrict__ A, const ushort_t* __restrict__ B, void* __restrict__ Cv,
    int M, int N, int K, int lda, int ldb, int ldc,
    int mode, int kPartLen)
{
  __shared__ ushort_t Alds[128*LSTR];
  __shared__ ushort_t Blds[128*LSTR];
  const int tid  = threadIdx.x;
  const int wave = tid >> 6, lane = tid & 63;
  const int wm = wave >> 1, wn = wave & 1;          // 4 x 2 wave grid
  const int col = lane & 15, quad = lane >> 4;
  const int m0 = blockIdx.y * 128, n0 = blockIdx.x * 128;
  int kStart = 0, kEnd = K;
  float*    C  = (float*)Cv;
  ushort_t* Cb = (ushort_t*)Cv;
  if (mode == 2) {
    kStart = blockIdx.z * kPartLen;
    kEnd = min(K, kStart + kPartLen);
    C += (size_t)blockIdx.z * (size_t)M * (size_t)ldc;
  }

  f32x4 acc[2][4];
  #pragma unroll
  for (int i = 0; i < 2; ++i)
    #pragma unroll
    for (int j = 0; j < 4; ++j)
      acc[i][j] = (f32x4){0.f,0.f,0.f,0.f};

  for (int k0 = kStart; k0 < kEnd; k0 += 64) {
    #pragma unroll
    for (int r = 0; r < 2; ++r) {
      const int u = tid + 512*r;
      const int mm = u >> 3, kg = u & 7;
      *(uint4*)&Alds[mm*LSTR + kg*8] = *(const uint4*)&A[(size_t)(m0+mm)*lda + k0 + kg*8];
      *(uint4*)&Blds[mm*LSTR + kg*8] = *(const uint4*)&B[(size_t)(n0+mm)*ldb + k0 + kg*8];
    }
    __syncthreads();
    #pragma unroll
    for (int ks = 0; ks < 2; ++ks) {
      bf16x8 af[2], bfr[4];
      #pragma unroll
      for (int t = 0; t < 2; ++t)
        af[t]  = *(bf16x8*)&Alds[(wm*32 + t*16 + col)*LSTR + ks*32 + quad*8];
      #pragma unroll
      for (int t = 0; t < 4; ++t)
        bfr[t] = *(bf16x8*)&Blds[(wn*64 + t*16 + col)*LSTR + ks*32 + quad*8];
      #pragma unroll
      for (int i = 0; i < 2; ++i)
        #pragma unroll
        for (int j = 0; j < 4; ++j)
          acc[i][j] = __builtin_amdgcn_mfma_f32_16x16x32_bf16(af[i], bfr[j], acc[i][j], 0, 0, 0);
    }
    __syncthreads();
  }

  // epilogue: C/D layout col = lane&15, row = quad*4 + reg
  #pragma unroll
  for (int i = 0; i < 2; ++i) {
    const int mBase = m0 + wm*32 + i*16 + quad*4;
    #pragma unroll
    for (int j = 0; j < 4; ++j) {
      const int n = n0 + wn*64 + j*16 + col;
      if (mode == 1) {
        #pragma unroll
        for (int r = 0; r < 4; ++r)
          Cb[(size_t)(mBase+r)*ldc + n] = f2bf(fmaxf(acc[i][j][r], 0.f));
      } else if (mode == 3) {
        #pragma unroll
        for (int r = 0; r < 4; ++r)
          Cb[(size_t)(mBase+r)*ldc + n] = f2bf(acc[i][j][r]);
      } else {
        #pragma unroll
        for (int r = 0; r < 4; ++r)
          C[(size_t)(mBase+r)*ldc + n] = acc[i][j][r];
      }
    }
  }
}

// ---------- gather_y v2: P-contraction + block-diag gather + rank-1 bias + 1/sqrt(512) ----------
// yPad[(b*8+g)*512 + j], j=soff(l)+u*d+m, i=l^2+m, col=l^2+u:
//   v = ( sum_h P[h][i] * T[(b*49+h)][g*64+col] + sumP[i]*bpsi[g*64+col] ) / sqrt(512)
// grid (8*NB) blocks (one per (b,g)), block 256; T-slice 49x64 fp32 staged in LDS.
__global__ __launch_bounds__(256) void gather_y(
    const float* __restrict__ T, const float* __restrict__ P,
    const float* __restrict__ sumP, const float* __restrict__ bpsi,
    ushort_t* __restrict__ y)
{
  __shared__ float Tg[49*64];
  __shared__ float Pl[49*49];
  __shared__ float sPl[49];
  __shared__ float bps[64];
  const int tid = threadIdx.x;
  const int g = blockIdx.x & 7, b = blockIdx.x >> 3;
  for (int idx = tid; idx < 49*64; idx += 256) {
    const int h = idx >> 6, c = idx & 63;
    Tg[idx] = T[(size_t)(b*49 + h)*512 + g*64 + c];
  }
  for (int idx = tid; idx < 2401; idx += 256) Pl[idx] = P[idx];
  if (tid < 49) sPl[tid] = sumP[tid];
  if (tid < 64) bps[tid] = bpsi[g*64 + tid];
  __syncthreads();
  #pragma unroll
  for (int rr = 0; rr < 2; ++rr) {
    const int j = tid + rr*256;
    float v = 0.f;
    if (j < SO3D) {
      int l;
      if (j < 1) l = 0; else if (j < 10) l = 1; else if (j < 35) l = 2;
      else if (j < 84) l = 3; else if (j < 165) l = 4; else if (j < 286) l = 5; else l = 6;
      const int so = soff(l), d = 2*l+1;
      const int r = j - so;
      const int u = r / d, m = r - u*d;
      const int i = l*l + m, colT = l*l + u;
      float acc = 0.f;
      #pragma unroll 7
      for (int h = 0; h < 49; ++h)
        acc = fmaf(Pl[h*49 + i], Tg[h*64 + colT], acc);
      v = (acc + sPl[i]*bps[colT]) * 0.044194173824159216f;
    }
    y[(size_t)(b*8+g)*512 + j] = f2bf(v);
  }
}

// ---------- final so3 conv: 8-partial sum + per-l contraction + fp32 store ----------
__global__ __launch_bounds__(512) void so3_final(
    const float* __restrict__ zpart, const float* __restrict__ psi2,
    float* __restrict__ out)
{
  __shared__ float Zs[8*SO3D];
  __shared__ float P2s[8*SO3D];
  const int b = blockIdx.x, tid = threadIdx.x;
  for (int idx = tid; idx < 8*SO3D; idx += 512) {
    const int f = idx / SO3D, i = idx - f*SO3D;
    float s = 0.f;
    #pragma unroll
    for (int p = 0; p < 8; ++p)
      s += zpart[((size_t)p*1024 + (size_t)b*FHID + f)*512 + i];
    Zs[idx] = s;
    P2s[idx] = psi2[idx];
  }
  __syncthreads();
  if (tid < SO3D) {
    const int i = tid;
    int l;
    if (i < 1) l = 0; else if (i < 10) l = 1; else if (i < 35) l = 2;
    else if (i < 84) l = 3; else if (i < 165) l = 4; else if (i < 286) l = 5; else l = 6;
    const int so = soff(l), d = 2*l+1;
    const int r = i - so;
    const int v = r / d, m = r - v*d;
    float acc = 0.f;
    for (int f = 0; f < 8; ++f)
      for (int u = 0; u < d; ++u)
        acc = fmaf(Zs[f*SO3D + so + u*d + m], P2s[f*SO3D + so + u*d + v], acc);
    const float scale = rsqrtf(8.0f * (float)d);
    out[(size_t)b*SO3D + i] = acc * scale;
  }
}

extern "C" void kernel_launch(void* const* d_in, const int* in_sizes, int n_in,
                              void* d_out, int out_size, void* d_ws, size_t ws_size,
                              hipStream_t stream) {
  const float* fmap    = (const float*)d_in[0];
  const float* conv_w  = (const float*)d_in[1];
  const float* conv_b  = (const float*)d_in[2];
  const float* proj_w  = (const float*)d_in[3];
  const float* proj_Y  = (const float*)d_in[4];
  const float* fs_w    = (const float*)d_in[5];
  const float* fs_Y    = (const float*)d_in[6];
  const float* act_to  = (const float*)d_in[7];
  const float* act_from= (const float*)d_in[8];
  const float* so3_w   = (const float*)d_in[9];
  const float* so3_D   = (const float*)d_in[10];
  float* out           = (float*)d_out;

  // workspace (bytes), lifetime-packed; max ~50.6 MB
  char* wsb = (char*)d_ws;
  float*    wP       = (float*)(wsb + 0);           // 49x49 fp32
  float*    wSumP    = (float*)(wsb + 9728);        // 64 fp32
  float*    wPsi2    = (float*)(wsb + 9984);        // 8x455 fp32 -> 24544, pad 24576
  ushort_t* actToT   = (ushort_t*)(wsb + 24576);    // 4096x512 bf16 -> 4218880
  ushort_t* actFromT = (ushort_t*)(wsb + 4218880);  // 512x4096 bf16 -> 8413184
  ushort_t* yPad     = (ushort_t*)(wsb + 8413184);  // 1024x512 bf16 -> 9461760
  ushort_t* psiT     = (ushort_t*)(wsb + 9461760);  // 512x512 bf16 -> 9986048
  float*    bpsi     = (float*)(wsb + 9986048);     // 512 fp32 -> 9988096
  ushort_t* W2T      = (ushort_t*)(wsb + 9988096);  // 512x2048 bf16 -> 12085248
  ushort_t* fmapT    = (ushort_t*)(wsb + 12085248); // 6272x2048 bf16 -> 37775360 (dead after T gemm)
  // X-region (all dead before T gemm), aliased by T:
  float*    wPsiP    = (float*)(wsb + 37775360);    // 4096x128 fp32 -> 39872512
  ushort_t* fswB     = (ushort_t*)(wsb + 39872512); // 4096x192 bf16 -> 41445376
  ushort_t* fsYT     = (ushort_t*)(wsb + 41445376); // 128x192 bf16  -> 41494528
  ushort_t* cwT      = (ushort_t*)(wsb + 41494528); // 2048x512 bf16 -> 43591680
  float*    Tbuf     = (float*)(wsb + 37775360);    // 6272x512 fp32 -> 50620416 (aliases X)
  // alias into dead fmapT region:
  ushort_t* gBuf     = (ushort_t*)(wsb + 12085248); // 1024x4096 bf16 -> 20473856
  float*    zPart    = (float*)(wsb + 20473856);    // 8x1024x512 fp32 -> 37251072

  const float is192 = 0.07216878364870323f;  // 1/sqrt(192)

  // --- prep ---
  gemm_nn<<<dim3(1,1), 256, 0, stream>>>(proj_w, proj_Y, wP, 49,49,192, 192,49,49, is192);
  gemm_nn<<<dim3(8,1), 256, 0, stream>>>(so3_w, so3_D, wPsi2, 8,455,192, 192,455,455, is192);
  sumP_kernel<<<dim3(1), 64, 0, stream>>>(wP, wSumP);
  cvt_bf16<<<dim3(768), 256, 0, stream>>>(fs_w, fswB, 4096*192);
  transpose_cvt<<<dim3(4,6),   256, 0, stream>>>(fs_Y, 192, 49, fsYT, 192, 128);
  transpose_cvt<<<dim3(128,16),256, 0, stream>>>(act_to, 455, 4000, actToT, 512, 4096);
  transpose_cvt<<<dim3(16,128),256, 0, stream>>>(act_from, 4000, 455, actFromT, 4096, 512);
  transpose_cvt<<<dim3(64,16), 256, 0, stream>>>(conv_w, 512, 2048, cwT, 512, 2048);
  transpose_fmap<<<dim3(32,128), 256, 0, stream>>>(fmap, fmapT);

  // wPsiP[(f,g)][ii(128)] = fs_w @ fs_Y   (M=4096, N=128, K=192), scale folded into prep_psiT
  gemm8_nt<<<dim3(1,32), 512, 0, stream>>>(fswB, fsYT, wPsiP,
      4096, 128, 192, 192, 192, 128, 0, 0);
  prep_psiT<<<dim3(1024), 256, 0, stream>>>(wPsiP, psiT);
  bpsi_kernel<<<dim3(128), 256, 0, stream>>>(psiT, conv_b, bpsi);

  // W2T[gi][c] = psiT @ cwT^T   (M=512, N=2048, K=512), bf16 out
  gemm8_nt<<<dim3(16,4), 512, 0, stream>>>(psiT, cwT, W2T,
      512, 2048, 512, 512, 512, 2048, 3, 0);
  // T[(b,h)][gi] = fmapT @ W2T^T   (M=6272, N=512, K=2048), fp32 out — fused conv+s2 (pre-projection)
  gemm8_nt<<<dim3(4,49), 512, 0, stream>>>(fmapT, W2T, Tbuf,
      6272, 512, 2048, 2048, 2048, 512, 0, 0);
  // yPad = P-contraction + block-diag gather + rank-1 bias + 1/sqrt(512)
  gather_y<<<dim3(1024), 256, 0, stream>>>(Tbuf, wP, wSumP, bpsi, yPad);
  // g = relu(yPad @ actToT^T) bf16   (M=1024, N=4096, K=512)
  gemm8_nt<<<dim3(32,8), 512, 0, stream>>>(yPad, actToT, gBuf,
      1024, 4096, 512, 512, 512, 4096, 1, 0);
  // zPart = gBuf @ actFromT^T, split-K=8   (M=1024, N=512, K=4096)
  gemm8_nt<<<dim3(4,8,8), 512, 0, stream>>>(gBuf, actFromT, zPart,
      1024, 512, 4096, 4096, 4096, 512, 2, 512);
  // final contraction + fp32 store
  so3_final<<<dim3(128), 512, 0, stream>>>(zPart, wPsi2, out);
}

// Round 9
// 306.963 us; speedup vs baseline: 2.6353x; 1.0145x over previous
//
#include <hip/hip_runtime.h>
#include <hip/hip_bf16.h>

#define NB    128
#define CENC  2048
#define FIN   512
#define FHID  8
#define S2D   49
#define SO3D  455
#define HW    49

typedef unsigned short ushort_t;
typedef __bf16 bf16x8 __attribute__((ext_vector_type(8)));
typedef float  f32x4  __attribute__((ext_vector_type(4)));

__device__ __forceinline__ int soff(int l) { return l*(4*l*l-1)/3; }  // sum_{l'<l}(2l'+1)^2

__device__ __forceinline__ ushort_t f2bf(float x) {
  __hip_bfloat16 h = __float2bfloat16(x);
  return *reinterpret_cast<ushort_t*>(&h);
}
__device__ __forceinline__ float bf2f(ushort_t u) {
  __hip_bfloat16 h = *reinterpret_cast<__hip_bfloat16*>(&u);
  return __bfloat162float(h);
}

// ---------- small fp32 GEMM (tiny preps only): C = alpha * A@B ----------
__global__ __launch_bounds__(256) void gemm_nn(
    const float* __restrict__ A, const float* __restrict__ B, float* __restrict__ C,
    int M, int N, int K, int lda, int ldb, int ldc, float alpha)
{
  __shared__ float As[32*68];
  __shared__ float Bs[32*68];
  const int tid = threadIdx.x;
  const int tx = tid & 15, ty = tid >> 4;
  const int n0 = blockIdx.x * 64, m0 = blockIdx.y * 64;
  float acc[4][4] = {};
  for (int k0 = 0; k0 < K; k0 += 32) {
    {
      const int kk = tid & 31, mmB = tid >> 5;
      #pragma unroll
      for (int j = 0; j < 8; ++j) {
        const int mm = mmB + 8*j;
        const int m = m0 + mm, k = k0 + kk;
        As[kk*68 + mm] = (m < M && k < K) ? A[(size_t)m*lda + k] : 0.f;
      }
    }
    {
      const int nn = tid & 63, kkB = tid >> 6;
      #pragma unroll
      for (int j = 0; j < 8; ++j) {
        const int kk = kkB + 4*j;
        const int n = n0 + nn, k = k0 + kk;
        Bs[kk*68 + nn] = (n < N && k < K) ? B[(size_t)k*ldb + n] : 0.f;
      }
    }
    __syncthreads();
    #pragma unroll
    for (int kk = 0; kk < 32; ++kk) {
      const float4 a4 = *(const float4*)&As[kk*68 + ty*4];
      const float4 b4 = *(const float4*)&Bs[kk*68 + tx*4];
      const float av[4] = {a4.x,a4.y,a4.z,a4.w};
      const float bv[4] = {b4.x,b4.y,b4.z,b4.w};
      #pragma unroll
      for (int i = 0; i < 4; ++i)
        #pragma unroll
        for (int j = 0; j < 4; ++j)
          acc[i][j] = fmaf(av[i], bv[j], acc[i][j]);
    }
    __syncthreads();
  }
  #pragma unroll
  for (int i = 0; i < 4; ++i) {
    const int m = m0 + ty*4 + i;
    if (m >= M) continue;
    #pragma unroll
    for (int j = 0; j < 4; ++j) {
      const int n = n0 + tx*4 + j;
      if (n >= N) continue;
      C[(size_t)m*ldc + n] = acc[i][j] * alpha;
    }
  }
}

// ---------- fp32 -> bf16 elementwise ----------
__global__ void cvt_bf16(const float* __restrict__ in, ushort_t* __restrict__ out, int n4) {
  int i = (blockIdx.x*256 + threadIdx.x)*4;
  if (i < n4) {
    float4 v = *(const float4*)&in[i];
    out[i+0] = f2bf(v.x); out[i+1] = f2bf(v.y);
    out[i+2] = f2bf(v.z); out[i+3] = f2bf(v.w);
  }
}

// ---------- transpose + cvt + pad: in fp32 [R][C] -> out bf16 [Cp][Rp] (zeros outside) ----------
__global__ __launch_bounds__(256) void transpose_cvt(
    const float* __restrict__ in, int R, int C,
    ushort_t* __restrict__ out, int Rp, int Cp)
{
  __shared__ float t[32][33];
  const int c0 = blockIdx.x*32, r0 = blockIdx.y*32;
  const int tx = threadIdx.x & 31, ty = threadIdx.x >> 5;
  #pragma unroll
  for (int j = 0; j < 4; ++j) {
    const int r = r0 + ty + j*8, c = c0 + tx;
    t[ty + j*8][tx] = (r < R && c < C) ? in[(size_t)r*C + c] : 0.f;
  }
  __syncthreads();
  #pragma unroll
  for (int j = 0; j < 4; ++j) {
    const int c = c0 + ty + j*8, r = r0 + tx;
    if (c < Cp && r < Rp) out[(size_t)c*Rp + r] = f2bf(t[tx][ty + j*8]);
  }
}

// ---------- fmapT[(b*49+h)][c] = bf16(fmap[b][c][h]) — pure transpose+cvt ----------
__global__ __launch_bounds__(256) void transpose_fmap(
    const float* __restrict__ fmap, ushort_t* __restrict__ out)
{
  __shared__ float Fs[64*49];   // [c_local][h]
  const int tid = threadIdx.x;
  const int cc = blockIdx.x, b = blockIdx.y;
  const int c0 = cc*64;
  const float* fsrc = fmap + ((size_t)b*CENC + c0)*HW;
  for (int idx = tid; idx < 784; idx += 256)
    *(float4*)&Fs[idx*4] = *(const float4*)&fsrc[idx*4];
  __syncthreads();
  for (int idx = tid; idx < 3136; idx += 256) {
    const int h = idx >> 6, cl = idx & 63;
    out[(size_t)(b*49 + h)*CENC + c0 + cl] = f2bf(Fs[cl*49 + h]);
  }
}

// ---------- sumP[i] = sum_h P[h][i] (P already has 1/sqrt(192) folded), i<49 ----------
__global__ void sumP_kernel(const float* __restrict__ P, float* __restrict__ sumP) {
  const int i = threadIdx.x;
  if (i < 64) {
    float s = 0.f;
    if (i < 49) for (int h = 0; h < 49; ++h) s += P[h*49 + i];
    sumP[i] = (i < 49) ? s : 0.f;
  }
}

// ---------- psiT[(g*64+ii)][f] = bf16( wPsiP[(f*8+g)*128 + ii] * 1/sqrt(192) ), ii>=49 -> 0 ----------
__global__ __launch_bounds__(256) void prep_psiT(
    const float* __restrict__ wPsiP, ushort_t* __restrict__ psiT)
{
  const int idx = blockIdx.x*256 + threadIdx.x;   // < 512*512
  const int row = idx >> 9, f = idx & 511;
  const int g = row >> 6, ii = row & 63;
  const float is192 = 0.07216878364870323f;
  psiT[idx] = (ii < 49) ? f2bf(wPsiP[(size_t)(f*8 + g)*128 + ii] * is192) : (ushort_t)0;
}

// ---------- bpsi[gi] = sum_f conv_b[f] * psiT[gi][f]  (wave per gi, coalesced) ----------
__global__ __launch_bounds__(256) void bpsi_kernel(
    const ushort_t* __restrict__ psiT, const float* __restrict__ conv_b,
    float* __restrict__ bpsi)
{
  const int w = threadIdx.x >> 6, lane = threadIdx.x & 63;
  const int gi = blockIdx.x*4 + w;
  float s = 0.f;
  #pragma unroll
  for (int s8 = 0; s8 < 8; ++s8) {
    const int f = s8*64 + lane;
    s += conv_b[f] * bf2f(psiT[(size_t)gi*512 + f]);
  }
  #pragma unroll
  for (int off = 32; off; off >>= 1) s += __shfl_down(s, off);
  if (lane == 0) bpsi[gi] = s;
}

// ---------- bf16 MFMA NT GEMM, 8 waves, tile 128x64 (R8: half-N tile doubles grid;
// occupancy dominated over per-block intensity at <=1 block/CU). C[m,n]=sum_k A[m,k]*B[n,k].
// M mult of 128, N mult of 64, K mult of 64. wave-tile 32x32 (wave grid 4x2), acc[2][2].
// mode 0: fp32 store | mode 1: relu->bf16 | mode 2: split-K fp32 partial | mode 3: bf16 store
#define LSTR 72
__global__ __launch_bounds__(512) void gemm8_nt(
    const ushort_t* __restrict__ A, const ushort_t* __restrict__ B, void* __restrict__ Cv,
    int M, int N, int K, int lda, int ldb, int ldc,
    int mode, int kPartLen)
{
  __shared__ ushort_t Alds[128*LSTR];
  __shared__ ushort_t Blds[64*LSTR];
  const int tid  = threadIdx.x;
  const int wave = tid >> 6, lane = tid & 63;
  const int wm = wave >> 1, wn = wave & 1;          // 4 x 2 wave grid
  const int col = lane & 15, quad = lane >> 4;
  const int m0 = blockIdx.y * 128, n0 = blockIdx.x * 64;
  int kStart = 0, kEnd = K;
  float*    C  = (float*)Cv;
  ushort_t* Cb = (ushort_t*)Cv;
  if (mode == 2) {
    kStart = blockIdx.z * kPartLen;
    kEnd = min(K, kStart + kPartLen);
    C += (size_t)blockIdx.z * (size_t)M * (size_t)ldc;
  }

  f32x4 acc[2][2];
  #pragma unroll
  for (int i = 0; i < 2; ++i)
    #pragma unroll
    for (int j = 0; j < 2; ++j)
      acc[i][j] = (f32x4){0.f,0.f,0.f,0.f};

  for (int k0 = kStart; k0 < kEnd; k0 += 64) {
    #pragma unroll
    for (int r = 0; r < 2; ++r) {
      const int u = tid + 512*r;
      const int mm = u >> 3, kg = u & 7;
      *(uint4*)&Alds[mm*LSTR + kg*8] = *(const uint4*)&A[(size_t)(m0+mm)*lda + k0 + kg*8];
    }
    {
      const int mm = tid >> 3, kg = tid & 7;
      if (mm < 64)
        *(uint4*)&Blds[mm*LSTR + kg*8] = *(const uint4*)&B[(size_t)(n0+mm)*ldb + k0 + kg*8];
    }
    __syncthreads();
    #pragma unroll
    for (int ks = 0; ks < 2; ++ks) {
      bf16x8 af[2], bfr[2];
      #pragma unroll
      for (int t = 0; t < 2; ++t) {
        af[t]  = *(bf16x8*)&Alds[(wm*32 + t*16 + col)*LSTR + ks*32 + quad*8];
        bfr[t] = *(bf16x8*)&Blds[(wn*32 + t*16 + col)*LSTR + ks*32 + quad*8];
      }
      #pragma unroll
      for (int i = 0; i < 2; ++i)
        #pragma unroll
        for (int j = 0; j < 2; ++j)
          acc[i][j] = __builtin_amdgcn_mfma_f32_16x16x32_bf16(af[i], bfr[j], acc[i][j], 0, 0, 0);
    }
    __syncthreads();
  }

  // epilogue: C/D layout col = lane&15, row = quad*4 + reg
  #pragma unroll
  for (int i = 0; i < 2; ++i) {
    const int mBase = m0 + wm*32 + i*16 + quad*4;
    #pragma unroll
    for (int j = 0; j < 2; ++j) {
      const int n = n0 + wn*32 + j*16 + col;
      if (mode == 1) {
        #pragma unroll
        for (int r = 0; r < 4; ++r)
          Cb[(size_t)(mBase+r)*ldc + n] = f2bf(fmaxf(acc[i][j][r], 0.f));
      } else if (mode == 3) {
        #pragma unroll
        for (int r = 0; r < 4; ++r)
          Cb[(size_t)(mBase+r)*ldc + n] = f2bf(acc[i][j][r]);
      } else {
        #pragma unroll
        for (int r = 0; r < 4; ++r)
          C[(size_t)(mBase+r)*ldc + n] = acc[i][j][r];
      }
    }
  }
}

// ---------- gather_y: P-contraction + block-diag gather + rank-1 bias + 1/sqrt(512) ----------
__global__ __launch_bounds__(256) void gather_y(
    const float* __restrict__ T, const float* __restrict__ P,
    const float* __restrict__ sumP, const float* __restrict__ bpsi,
    ushort_t* __restrict__ y)
{
  __shared__ float Tg[49*64];
  __shared__ float Pl[49*49];
  __shared__ float sPl[49];
  __shared__ float bps[64];
  const int tid = threadIdx.x;
  const int g = blockIdx.x & 7, b = blockIdx.x >> 3;
  for (int idx = tid; idx < 49*64; idx += 256) {
    const int h = idx >> 6, c = idx & 63;
    Tg[idx] = T[(size_t)(b*49 + h)*512 + g*64 + c];
  }
  for (int idx = tid; idx < 2401; idx += 256) Pl[idx] = P[idx];
  if (tid < 49) sPl[tid] = sumP[tid];
  if (tid < 64) bps[tid] = bpsi[g*64 + tid];
  __syncthreads();
  #pragma unroll
  for (int rr = 0; rr < 2; ++rr) {
    const int j = tid + rr*256;
    float v = 0.f;
    if (j < SO3D) {
      int l;
      if (j < 1) l = 0; else if (j < 10) l = 1; else if (j < 35) l = 2;
      else if (j < 84) l = 3; else if (j < 165) l = 4; else if (j < 286) l = 5; else l = 6;
      const int so = soff(l), d = 2*l+1;
      const int r = j - so;
      const int u = r / d, m = r - u*d;
      const int i = l*l + m, colT = l*l + u;
      float acc = 0.f;
      #pragma unroll 7
      for (int h = 0; h < 49; ++h)
        acc = fmaf(Pl[h*49 + i], Tg[h*64 + colT], acc);
      v = (acc + sPl[i]*bps[colT]) * 0.044194173824159216f;
    }
    y[(size_t)(b*8+g)*512 + j] = f2bf(v);
  }
}

// ---------- final so3 conv: 8-partial sum + per-l contraction + fp32 store ----------
__global__ __launch_bounds__(512) void so3_final(
    const float* __restrict__ zpart, const float* __restrict__ psi2,
    float* __restrict__ out)
{
  __shared__ float Zs[8*SO3D];
  __shared__ float P2s[8*SO3D];
  const int b = blockIdx.x, tid = threadIdx.x;
  for (int idx = tid; idx < 8*SO3D; idx += 512) {
    const int f = idx / SO3D, i = idx - f*SO3D;
    float s = 0.f;
    #pragma unroll
    for (int p = 0; p < 8; ++p)
      s += zpart[((size_t)p*1024 + (size_t)b*FHID + f)*512 + i];
    Zs[idx] = s;
    P2s[idx] = psi2[idx];
  }
  __syncthreads();
  if (tid < SO3D) {
    const int i = tid;
    int l;
    if (i < 1) l = 0; else if (i < 10) l = 1; else if (i < 35) l = 2;
    else if (i < 84) l = 3; else if (i < 165) l = 4; else if (i < 286) l = 5; else l = 6;
    const int so = soff(l), d = 2*l+1;
    const int r = i - so;
    const int v = r / d, m = r - v*d;
    float acc = 0.f;
    for (int f = 0; f < 8; ++f)
      for (int u = 0; u < d; ++u)
        acc = fmaf(Zs[f*SO3D + so + u*d + m], P2s[f*SO3D + so + u*d + v], acc);
    const float scale = rsqrtf(8.0f * (float)d);
    out[(size_t)b*SO3D + i] = acc * scale;
  }
}

extern "C" void kernel_launch(void* const* d_in, const int* in_sizes, int n_in,
                              void* d_out, int out_size, void* d_ws, size_t ws_size,
                              hipStream_t stream) {
  const float* fmap    = (const float*)d_in[0];
  const float* conv_w  = (const float*)d_in[1];
  const float* conv_b  = (const float*)d_in[2];
  const float* proj_w  = (const float*)d_in[3];
  const float* proj_Y  = (const float*)d_in[4];
  const float* fs_w    = (const float*)d_in[5];
  const float* fs_Y    = (const float*)d_in[6];
  const float* act_to  = (const float*)d_in[7];
  const float* act_from= (const float*)d_in[8];
  const float* so3_w   = (const float*)d_in[9];
  const float* so3_D   = (const float*)d_in[10];
  float* out           = (float*)d_out;

  // workspace (bytes), lifetime-packed; max ~50.6 MB
  char* wsb = (char*)d_ws;
  float*    wP       = (float*)(wsb + 0);           // 49x49 fp32
  float*    wSumP    = (float*)(wsb + 9728);        // 64 fp32
  float*    wPsi2    = (float*)(wsb + 9984);        // 8x455 fp32 -> 24544, pad 24576
  ushort_t* actToT   = (ushort_t*)(wsb + 24576);    // 4096x512 bf16 -> 4218880
  ushort_t* actFromT = (ushort_t*)(wsb + 4218880);  // 512x4096 bf16 -> 8413184
  ushort_t* yPad     = (ushort_t*)(wsb + 8413184);  // 1024x512 bf16 -> 9461760
  ushort_t* psiT     = (ushort_t*)(wsb + 9461760);  // 512x512 bf16 -> 9986048
  float*    bpsi     = (float*)(wsb + 9986048);     // 512 fp32 -> 9988096
  ushort_t* W2T      = (ushort_t*)(wsb + 9988096);  // 512x2048 bf16 -> 12085248
  ushort_t* fmapT    = (ushort_t*)(wsb + 12085248); // 6272x2048 bf16 -> 37775360 (dead after T gemm)
  // X-region (all dead before T gemm), aliased by T:
  float*    wPsiP    = (float*)(wsb + 37775360);    // 4096x128 fp32 -> 39872512
  ushort_t* fswB     = (ushort_t*)(wsb + 39872512); // 4096x192 bf16 -> 41445376
  ushort_t* fsYT     = (ushort_t*)(wsb + 41445376); // 128x192 bf16  -> 41494528
  ushort_t* cwT      = (ushort_t*)(wsb + 41494528); // 2048x512 bf16 -> 43591680
  float*    Tbuf     = (float*)(wsb + 37775360);    // 6272x512 fp32 -> 50620416 (aliases X)
  // alias into dead fmapT region:
  ushort_t* gBuf     = (ushort_t*)(wsb + 12085248); // 1024x4096 bf16 -> 20473856
  float*    zPart    = (float*)(wsb + 20473856);    // 8x1024x512 fp32 -> 37251072

  const float is192 = 0.07216878364870323f;  // 1/sqrt(192)

  // --- prep ---
  gemm_nn<<<dim3(1,1), 256, 0, stream>>>(proj_w, proj_Y, wP, 49,49,192, 192,49,49, is192);
  gemm_nn<<<dim3(8,1), 256, 0, stream>>>(so3_w, so3_D, wPsi2, 8,455,192, 192,455,455, is192);
  sumP_kernel<<<dim3(1), 64, 0, stream>>>(wP, wSumP);
  cvt_bf16<<<dim3(768), 256, 0, stream>>>(fs_w, fswB, 4096*192);
  transpose_cvt<<<dim3(4,6),   256, 0, stream>>>(fs_Y, 192, 49, fsYT, 192, 128);
  transpose_cvt<<<dim3(128,16),256, 0, stream>>>(act_to, 455, 4000, actToT, 512, 4096);
  transpose_cvt<<<dim3(16,128),256, 0, stream>>>(act_from, 4000, 455, actFromT, 4096, 512);
  transpose_cvt<<<dim3(64,16), 256, 0, stream>>>(conv_w, 512, 2048, cwT, 512, 2048);
  transpose_fmap<<<dim3(32,128), 256, 0, stream>>>(fmap, fmapT);

  // wPsiP[(f,g)][ii(128)] = fs_w @ fs_Y   (M=4096, N=128, K=192)
  gemm8_nt<<<dim3(2,32), 512, 0, stream>>>(fswB, fsYT, wPsiP,
      4096, 128, 192, 192, 192, 128, 0, 0);
  prep_psiT<<<dim3(1024), 256, 0, stream>>>(wPsiP, psiT);
  bpsi_kernel<<<dim3(128), 256, 0, stream>>>(psiT, conv_b, bpsi);

  // W2T[gi][c] = psiT @ cwT^T   (M=512, N=2048, K=512), bf16 out
  gemm8_nt<<<dim3(32,4), 512, 0, stream>>>(psiT, cwT, W2T,
      512, 2048, 512, 512, 512, 2048, 3, 0);
  // T[(b,h)][gi] = fmapT @ W2T^T   (M=6272, N=512, K=2048), fp32 out
  gemm8_nt<<<dim3(8,49), 512, 0, stream>>>(fmapT, W2T, Tbuf,
      6272, 512, 2048, 2048, 2048, 512, 0, 0);
  // yPad = P-contraction + block-diag gather + rank-1 bias + 1/sqrt(512)
  gather_y<<<dim3(1024), 256, 0, stream>>>(Tbuf, wP, wSumP, bpsi, yPad);
  // g = relu(yPad @ actToT^T) bf16   (M=1024, N=4096, K=512)
  gemm8_nt<<<dim3(64,8), 512, 0, stream>>>(yPad, actToT, gBuf,
      1024, 4096, 512, 512, 512, 4096, 1, 0);
  // zPart = gBuf @ actFromT^T, split-K=8   (M=1024, N=512, K=4096)
  gemm8_nt<<<dim3(8,8,8), 512, 0, stream>>>(gBuf, actFromT, zPart,
      1024, 512, 4096, 4096, 4096, 512, 2, 512);
  // final contraction + fp32 store
  so3_final<<<dim3(128), 512, 0, stream>>>(zPart, wPsi2, out);
}

// Round 10
// 254.406 us; speedup vs baseline: 3.1797x; 1.2066x over previous
//
#include <hip/hip_runtime.h>
#include <hip/hip_bf16.h>

#define NB    128
#define CENC  2048
#define FIN   512
#define FHID  8
#define S2D   49
#define SO3D  455
#define HW    49

typedef unsigned short ushort_t;
typedef __bf16 bf16x8 __attribute__((ext_vector_type(8)));
typedef float  f32x4  __attribute__((ext_vector_type(4)));

__device__ __forceinline__ int soff(int l) { return l*(4*l*l-1)/3; }  // sum_{l'<l}(2l'+1)^2

__device__ __forceinline__ ushort_t f2bf(float x) {
  __hip_bfloat16 h = __float2bfloat16(x);
  return *reinterpret_cast<ushort_t*>(&h);
}
__device__ __forceinline__ float bf2f(ushort_t u) {
  __hip_bfloat16 h = *reinterpret_cast<__hip_bfloat16*>(&u);
  return __bfloat162float(h);
}

// ================= device building blocks for the fused prep kernel =================

// fp32 GEMM tile: C[m0+.., n0+..] = alpha * A@B, 64x64 tile, 256 threads, smem >= 2*32*68 floats
__device__ __forceinline__ void dev_gemm_nn(float* smem,
    const float* __restrict__ A, const float* __restrict__ B, float* __restrict__ C,
    int M, int N, int K, int lda, int ldb, int ldc, float alpha, int bx, int by)
{
  float* As = smem;
  float* Bs = smem + 32*68;
  const int tid = threadIdx.x;
  const int tx = tid & 15, ty = tid >> 4;
  const int n0 = bx * 64, m0 = by * 64;
  float acc[4][4] = {};
  for (int k0 = 0; k0 < K; k0 += 32) {
    {
      const int kk = tid & 31, mmB = tid >> 5;
      #pragma unroll
      for (int j = 0; j < 8; ++j) {
        const int mm = mmB + 8*j;
        const int m = m0 + mm, k = k0 + kk;
        As[kk*68 + mm] = (m < M && k < K) ? A[(size_t)m*lda + k] : 0.f;
      }
    }
    {
      const int nn = tid & 63, kkB = tid >> 6;
      #pragma unroll
      for (int j = 0; j < 8; ++j) {
        const int kk = kkB + 4*j;
        const int n = n0 + nn, k = k0 + kk;
        Bs[kk*68 + nn] = (n < N && k < K) ? B[(size_t)k*ldb + n] : 0.f;
      }
    }
    __syncthreads();
    #pragma unroll
    for (int kk = 0; kk < 32; ++kk) {
      const float4 a4 = *(const float4*)&As[kk*68 + ty*4];
      const float4 b4 = *(const float4*)&Bs[kk*68 + tx*4];
      const float av[4] = {a4.x,a4.y,a4.z,a4.w};
      const float bv[4] = {b4.x,b4.y,b4.z,b4.w};
      #pragma unroll
      for (int i = 0; i < 4; ++i)
        #pragma unroll
        for (int j = 0; j < 4; ++j)
          acc[i][j] = fmaf(av[i], bv[j], acc[i][j]);
    }
    __syncthreads();
  }
  #pragma unroll
  for (int i = 0; i < 4; ++i) {
    const int m = m0 + ty*4 + i;
    if (m >= M) continue;
    #pragma unroll
    for (int j = 0; j < 4; ++j) {
      const int n = n0 + tx*4 + j;
      if (n >= N) continue;
      C[(size_t)m*ldc + n] = acc[i][j] * alpha;
    }
  }
}

// transpose + cvt + pad: in fp32 [R][C] -> out bf16 [Cp][Rp]; 32x32 tile at (bx,by)
__device__ __forceinline__ void dev_transpose_cvt(float* smem,
    const float* __restrict__ in, int R, int C,
    ushort_t* __restrict__ out, int Rp, int Cp, int bx, int by)
{
  float (*t)[33] = (float(*)[33])smem;
  const int c0 = bx*32, r0 = by*32;
  const int tx = threadIdx.x & 31, ty = threadIdx.x >> 5;
  #pragma unroll
  for (int j = 0; j < 4; ++j) {
    const int r = r0 + ty + j*8, c = c0 + tx;
    t[ty + j*8][tx] = (r < R && c < C) ? in[(size_t)r*C + c] : 0.f;
  }
  __syncthreads();
  #pragma unroll
  for (int j = 0; j < 4; ++j) {
    const int c = c0 + ty + j*8, r = r0 + tx;
    if (c < Cp && r < Rp) out[(size_t)c*Rp + r] = f2bf(t[tx][ty + j*8]);
  }
}

// fmapT[(b*49+h)][c] = bf16(fmap[b][c][h]); 64-c slab per block
__device__ __forceinline__ void dev_transpose_fmap(float* smem,
    const float* __restrict__ fmap, ushort_t* __restrict__ out, int cc, int b)
{
  float* Fs = smem;   // [c_local][h], 64*49
  const int tid = threadIdx.x;
  const int c0 = cc*64;
  const float* fsrc = fmap + ((size_t)b*CENC + c0)*HW;
  for (int idx = tid; idx < 784; idx += 256)
    *(float4*)&Fs[idx*4] = *(const float4*)&fsrc[idx*4];
  __syncthreads();
  for (int idx = tid; idx < 3136; idx += 256) {
    const int h = idx >> 6, cl = idx & 63;
    out[(size_t)(b*49 + h)*CENC + c0 + cl] = f2bf(Fs[cl*49 + h]);
  }
}

// sumP[i] = is192 * sum_h (proj_w @ proj_Y)[h][i] = is192 * sum_k colsum_w[k]*proj_Y[k][i]
__device__ __forceinline__ void dev_sumP(float* smem,
    const float* __restrict__ proj_w, const float* __restrict__ proj_Y,
    float* __restrict__ sumP)
{
  float* colsum = smem;   // 192 floats
  const int tid = threadIdx.x;
  if (tid < 192) {
    float s = 0.f;
    for (int h = 0; h < 49; ++h) s += proj_w[h*192 + tid];
    colsum[tid] = s;
  }
  __syncthreads();
  if (tid < 64) {
    float s = 0.f;
    if (tid < 49) for (int k = 0; k < 192; ++k) s += colsum[k] * proj_Y[k*49 + tid];
    sumP[tid] = (tid < 49) ? s * 0.07216878364870323f : 0.f;
  }
}

// ================= fused prep kernel: all independent prep work in ONE dispatch =================
// ranges: [0,1) P gemm | [1,9) psi2 gemm | [9,73) psi gemm (fp32, direct) |
// [73,2121) act_to^T | [2121,4169) act_from^T | [4169,5193) conv_w^T | [5193,9289) fmap^T | [9289] sumP
__global__ __launch_bounds__(256) void prep_all(
    const float* __restrict__ fmap, const float* __restrict__ conv_w,
    const float* __restrict__ proj_w, const float* __restrict__ proj_Y,
    const float* __restrict__ fs_w, const float* __restrict__ fs_Y,
    const float* __restrict__ act_to, const float* __restrict__ act_from,
    const float* __restrict__ so3_w, const float* __restrict__ so3_D,
    float* __restrict__ wP, float* __restrict__ wSumP, float* __restrict__ wPsi2,
    float* __restrict__ wPsiP,
    ushort_t* __restrict__ actToT, ushort_t* __restrict__ actFromT,
    ushort_t* __restrict__ cwT, ushort_t* __restrict__ fmapT)
{
  __shared__ float smem[32*68*2];
  const int blk = blockIdx.x;
  const float is192 = 0.07216878364870323f;
  if (blk < 1) {
    dev_gemm_nn(smem, proj_w, proj_Y, wP, 49,49,192, 192,49,49, is192, 0, 0);
  } else if (blk < 9) {
    dev_gemm_nn(smem, so3_w, so3_D, wPsi2, 8,455,192, 192,455,455, is192, blk-1, 0);
  } else if (blk < 73) {
    dev_gemm_nn(smem, fs_w, fs_Y, wPsiP, 4096,49,192, 192,49,128, is192, 0, blk-9);
  } else if (blk < 2121) {
    const int t = blk-73;   dev_transpose_cvt(smem, act_to, 455, 4000, actToT, 512, 4096, t & 127, t >> 7);
  } else if (blk < 4169) {
    const int t = blk-2121; dev_transpose_cvt(smem, act_from, 4000, 455, actFromT, 4096, 512, t & 15, t >> 4);
  } else if (blk < 5193) {
    const int t = blk-4169; dev_transpose_cvt(smem, conv_w, 512, 2048, cwT, 512, 2048, t & 63, t >> 6);
  } else if (blk < 9289) {
    const int t = blk-5193; dev_transpose_fmap(smem, fmap, fmapT, t & 31, t >> 5);
  } else {
    dev_sumP(smem, proj_w, proj_Y, wSumP);
  }
}

// ============ psiT cvt + bpsi + Tbuf zero-init, one dispatch ============
// [0,1024): psiT[(g*64+ii)*512+f] = bf16(wPsiP[(f*8+g)*128+ii]) (ii>=49 -> 0)
// [1024,1152): bpsi[gi] = sum_f conv_b[f]*round_bf16(wPsiP[...])
// [1152,1936): zero Tbuf (6272*512 fp32) for atomic split-K
__global__ __launch_bounds__(256) void psiT_bpsi(
    const float* __restrict__ wPsiP, const float* __restrict__ conv_b,
    ushort_t* __restrict__ psiT, float* __restrict__ bpsi, float* __restrict__ Tbuf)
{
  const int blk = blockIdx.x, tid = threadIdx.x;
  if (blk < 1024) {
    const int idx = blk*256 + tid;
    const int row = idx >> 9, f = idx & 511;
    const int g = row >> 6, ii = row & 63;
    psiT[idx] = (ii < 49) ? f2bf(wPsiP[(size_t)(f*8 + g)*128 + ii]) : (ushort_t)0;
  } else if (blk < 1152) {
    const int w = tid >> 6, lane = tid & 63;
    const int gi = (blk-1024)*4 + w;
    const int g = gi >> 6, ii = gi & 63;
    float s = 0.f;
    if (ii < 49) {
      #pragma unroll
      for (int s8 = 0; s8 < 8; ++s8) {
        const int f = s8*64 + lane;
        s += conv_b[f] * bf2f(f2bf(wPsiP[(size_t)(f*8 + g)*128 + ii]));
      }
    }
    #pragma unroll
    for (int off = 32; off; off >>= 1) s += __shfl_down(s, off);
    if (lane == 0) bpsi[gi] = s;
  } else {
    const int t = blk - 1152;
    float4* p = (float4*)Tbuf;
    const float4 z = (float4){0.f,0.f,0.f,0.f};
    #pragma unroll
    for (int j = 0; j < 4; ++j)
      p[t*1024 + j*256 + tid] = z;
  }
}

// ---------- bf16 MFMA NT GEMM, 8 waves, tile 128x64. C[m,n]=sum_k A[m,k]*B[n,k] ----------
// mode 0: fp32 store | mode 1: relu->bf16 | mode 2: split-K fp32 partial buffers |
// mode 3: bf16 store | mode 4: split-K fp32 atomicAdd (C must be zeroed; 2 adds = commutative)
#define LSTR 72
__global__ __launch_bounds__(512) void gemm8_nt(
    const ushort_t* __restrict__ A, const ushort_t* __restrict__ B, void* __restrict__ Cv,
    int M, int N, int K, int lda, int ldb, int ldc,
    int mode, int kPartLen)
{
  __shared__ ushort_t Alds[128*LSTR];
  __shared__ ushort_t Blds[64*LSTR];
  const int tid  = threadIdx.x;
  const int wave = tid >> 6, lane = tid & 63;
  const int wm = wave >> 1, wn = wave & 1;          // 4 x 2 wave grid
  const int col = lane & 15, quad = lane >> 4;
  const int m0 = blockIdx.y * 128, n0 = blockIdx.x * 64;
  int kStart = 0, kEnd = K;
  float*    C  = (float*)Cv;
  ushort_t* Cb = (ushort_t*)Cv;
  if (mode == 2) {
    kStart = blockIdx.z * kPartLen;
    kEnd = min(K, kStart + kPartLen);
    C += (size_t)blockIdx.z * (size_t)M * (size_t)ldc;
  } else if (mode == 4) {
    kStart = blockIdx.z * kPartLen;
    kEnd = min(K, kStart + kPartLen);
  }

  f32x4 acc[2][2];
  #pragma unroll
  for (int i = 0; i < 2; ++i)
    #pragma unroll
    for (int j = 0; j < 2; ++j)
      acc[i][j] = (f32x4){0.f,0.f,0.f,0.f};

  for (int k0 = kStart; k0 < kEnd; k0 += 64) {
    #pragma unroll
    for (int r = 0; r < 2; ++r) {
      const int u = tid + 512*r;
      const int mm = u >> 3, kg = u & 7;
      *(uint4*)&Alds[mm*LSTR + kg*8] = *(const uint4*)&A[(size_t)(m0+mm)*lda + k0 + kg*8];
    }
    {
      const int mm = tid >> 3, kg = tid & 7;
      if (mm < 64)
        *(uint4*)&Blds[mm*LSTR + kg*8] = *(const uint4*)&B[(size_t)(n0+mm)*ldb + k0 + kg*8];
    }
    __syncthreads();
    #pragma unroll
    for (int ks = 0; ks < 2; ++ks) {
      bf16x8 af[2], bfr[2];
      #pragma unroll
      for (int t = 0; t < 2; ++t) {
        af[t]  = *(bf16x8*)&Alds[(wm*32 + t*16 + col)*LSTR + ks*32 + quad*8];
        bfr[t] = *(bf16x8*)&Blds[(wn*32 + t*16 + col)*LSTR + ks*32 + quad*8];
      }
      #pragma unroll
      for (int i = 0; i < 2; ++i)
        #pragma unroll
        for (int j = 0; j < 2; ++j)
          acc[i][j] = __builtin_amdgcn_mfma_f32_16x16x32_bf16(af[i], bfr[j], acc[i][j], 0, 0, 0);
    }
    __syncthreads();
  }

  // epilogue: C/D layout col = lane&15, row = quad*4 + reg
  #pragma unroll
  for (int i = 0; i < 2; ++i) {
    const int mBase = m0 + wm*32 + i*16 + quad*4;
    #pragma unroll
    for (int j = 0; j < 2; ++j) {
      const int n = n0 + wn*32 + j*16 + col;
      if (mode == 1) {
        #pragma unroll
        for (int r = 0; r < 4; ++r)
          Cb[(size_t)(mBase+r)*ldc + n] = f2bf(fmaxf(acc[i][j][r], 0.f));
      } else if (mode == 3) {
        #pragma unroll
        for (int r = 0; r < 4; ++r)
          Cb[(size_t)(mBase+r)*ldc + n] = f2bf(acc[i][j][r]);
      } else if (mode == 4) {
        #pragma unroll
        for (int r = 0; r < 4; ++r)
          atomicAdd(&C[(size_t)(mBase+r)*ldc + n], acc[i][j][r]);
      } else {
        #pragma unroll
        for (int r = 0; r < 4; ++r)
          C[(size_t)(mBase+r)*ldc + n] = acc[i][j][r];
      }
    }
  }
}

// ---------- gather_y: P-contraction + block-diag gather + rank-1 bias + 1/sqrt(512) ----------
__global__ __launch_bounds__(256) void gather_y(
    const float* __restrict__ T, const float* __restrict__ P,
    const float* __restrict__ sumP, const float* __restrict__ bpsi,
    ushort_t* __restrict__ y)
{
  __shared__ float Tg[49*64];
  __shared__ float Pl[49*49];
  __shared__ float sPl[49];
  __shared__ float bps[64];
  const int tid = threadIdx.x;
  const int g = blockIdx.x & 7, b = blockIdx.x >> 3;
  for (int idx = tid; idx < 49*64; idx += 256) {
    const int h = idx >> 6, c = idx & 63;
    Tg[idx] = T[(size_t)(b*49 + h)*512 + g*64 + c];
  }
  for (int idx = tid; idx < 2401; idx += 256) Pl[idx] = P[idx];
  if (tid < 49) sPl[tid] = sumP[tid];
  if (tid < 64) bps[tid] = bpsi[g*64 + tid];
  __syncthreads();
  #pragma unroll
  for (int rr = 0; rr < 2; ++rr) {
    const int j = tid + rr*256;
    float v = 0.f;
    if (j < SO3D) {
      int l;
      if (j < 1) l = 0; else if (j < 10) l = 1; else if (j < 35) l = 2;
      else if (j < 84) l = 3; else if (j < 165) l = 4; else if (j < 286) l = 5; else l = 6;
      const int so = soff(l), d = 2*l+1;
      const int r = j - so;
      const int u = r / d, m = r - u*d;
      const int i = l*l + m, colT = l*l + u;
      float acc = 0.f;
      #pragma unroll 7
      for (int h = 0; h < 49; ++h)
        acc = fmaf(Pl[h*49 + i], Tg[h*64 + colT], acc);
      v = (acc + sPl[i]*bps[colT]) * 0.044194173824159216f;
    }
    y[(size_t)(b*8+g)*512 + j] = f2bf(v);
  }
}

// ---------- final so3 conv: 8-partial sum + per-l contraction + fp32 store ----------
__global__ __launch_bounds__(512) void so3_final(
    const float* __restrict__ zpart, const float* __restrict__ psi2,
    float* __restrict__ out)
{
  __shared__ float Zs[8*SO3D];
  __shared__ float P2s[8*SO3D];
  const int b = blockIdx.x, tid = threadIdx.x;
  for (int idx = tid; idx < 8*SO3D; idx += 512) {
    const int f = idx / SO3D, i = idx - f*SO3D;
    float s = 0.f;
    #pragma unroll
    for (int p = 0; p < 8; ++p)
      s += zpart[((size_t)p*1024 + (size_t)b*FHID + f)*512 + i];
    Zs[idx] = s;
    P2s[idx] = psi2[idx];
  }
  __syncthreads();
  if (tid < SO3D) {
    const int i = tid;
    int l;
    if (i < 1) l = 0; else if (i < 10) l = 1; else if (i < 35) l = 2;
    else if (i < 84) l = 3; else if (i < 165) l = 4; else if (i < 286) l = 5; else l = 6;
    const int so = soff(l), d = 2*l+1;
    const int r = i - so;
    const int v = r / d, m = r - v*d;
    float acc = 0.f;
    for (int f = 0; f < 8; ++f)
      for (int u = 0; u < d; ++u)
        acc = fmaf(Zs[f*SO3D + so + u*d + m], P2s[f*SO3D + so + u*d + v], acc);
    const float scale = rsqrtf(8.0f * (float)d);
    out[(size_t)b*SO3D + i] = acc * scale;
  }
}

extern "C" void kernel_launch(void* const* d_in, const int* in_sizes, int n_in,
                              void* d_out, int out_size, void* d_ws, size_t ws_size,
                              hipStream_t stream) {
  const float* fmap    = (const float*)d_in[0];
  const float* conv_w  = (const float*)d_in[1];
  const float* conv_b  = (const float*)d_in[2];
  const float* proj_w  = (const float*)d_in[3];
  const float* proj_Y  = (const float*)d_in[4];
  const float* fs_w    = (const float*)d_in[5];
  const float* fs_Y    = (const float*)d_in[6];
  const float* act_to  = (const float*)d_in[7];
  const float* act_from= (const float*)d_in[8];
  const float* so3_w   = (const float*)d_in[9];
  const float* so3_D   = (const float*)d_in[10];
  float* out           = (float*)d_out;

  // workspace (bytes), lifetime-packed; max ~54.8 MB
  char* wsb = (char*)d_ws;
  float*    wP       = (float*)(wsb + 0);           // 49x49 fp32
  float*    wSumP    = (float*)(wsb + 9728);        // 64 fp32
  float*    wPsi2    = (float*)(wsb + 9984);        // 8x455 fp32 -> 24544, pad 24576
  ushort_t* actToT   = (ushort_t*)(wsb + 24576);    // 4096x512 bf16 -> 4218880
  ushort_t* actFromT = (ushort_t*)(wsb + 4218880);  // 512x4096 bf16 -> 8413184
  ushort_t* yPad     = (ushort_t*)(wsb + 8413184);  // 1024x512 bf16 -> 9461760
  ushort_t* psiT     = (ushort_t*)(wsb + 9461760);  // 512x512 bf16 -> 9986048
  float*    bpsi     = (float*)(wsb + 9986048);     // 512 fp32 -> 9988096
  ushort_t* W2T      = (ushort_t*)(wsb + 9988096);  // 512x2048 bf16 -> 12085248
  ushort_t* fmapT    = (ushort_t*)(wsb + 12085248); // 6272x2048 bf16 -> 37775360 (dead after T gemm)
  float*    wPsiP    = (float*)(wsb + 37775360);    // 4096x128 fp32 -> 39872512 (dead after psiT_bpsi)
  ushort_t* cwT      = (ushort_t*)(wsb + 39872512); // 2048x512 bf16 -> 41969664 (dead after W2T gemm)
  float*    Tbuf     = (float*)(wsb + 41969664);    // 6272x512 fp32 -> 54814720
  // aliases into dead fmapT region:
  ushort_t* gBuf     = (ushort_t*)(wsb + 12085248); // 1024x4096 bf16 -> 20473856
  float*    zPart    = (float*)(wsb + 20473856);    // 8x1024x512 fp32 -> 37251072

  // 1) ALL independent prep in one dispatch (9290 blocks)
  prep_all<<<dim3(9290), 256, 0, stream>>>(
      fmap, conv_w, proj_w, proj_Y, fs_w, fs_Y, act_to, act_from, so3_w, so3_D,
      wP, wSumP, wPsi2, wPsiP, actToT, actFromT, cwT, fmapT);
  // 2) psiT cvt + bpsi + Tbuf zero (1936 blocks)
  psiT_bpsi<<<dim3(1936), 256, 0, stream>>>(wPsiP, conv_b, psiT, bpsi, Tbuf);
  // 3) W2T[gi][c] = psiT @ cwT^T   (M=512, N=2048, K=512), bf16 out
  gemm8_nt<<<dim3(32,4), 512, 0, stream>>>(psiT, cwT, W2T,
      512, 2048, 512, 512, 512, 2048, 3, 0);
  // 4) T[(b,h)][gi] = fmapT @ W2T^T  (M=6272, N=512, K=2048), split-K=2 atomic fp32
  gemm8_nt<<<dim3(8,49,2), 512, 0, stream>>>(fmapT, W2T, Tbuf,
      6272, 512, 2048, 2048, 2048, 512, 4, 1024);
  // 5) yPad = P-contraction + block-diag gather + rank-1 bias + 1/sqrt(512)
  gather_y<<<dim3(1024), 256, 0, stream>>>(Tbuf, wP, wSumP, bpsi, yPad);
  // 6) g = relu(yPad @ actToT^T) bf16   (M=1024, N=4096, K=512)
  gemm8_nt<<<dim3(64,8), 512, 0, stream>>>(yPad, actToT, gBuf,
      1024, 4096, 512, 512, 512, 4096, 1, 0);
  // 7) zPart = gBuf @ actFromT^T, split-K=8 partial buffers  (M=1024, N=512, K=4096)
  gemm8_nt<<<dim3(8,8,8), 512, 0, stream>>>(gBuf, actFromT, zPart,
      1024, 512, 4096, 4096, 4096, 512, 2, 512);
  // 8) final contraction + fp32 store
  so3_final<<<dim3(128), 512, 0, stream>>>(zPart, wPsi2, out);
}

// Round 11
// 230.713 us; speedup vs baseline: 3.5063x; 1.1027x over previous
//
#include <hip/hip_runtime.h>
#include <hip/hip_bf16.h>

#define NB    128
#define CENC  2048
#define FIN   512
#define FHID  8
#define S2D   49
#define SO3D  455
#define HW    49

typedef unsigned short ushort_t;
typedef __bf16 bf16x8 __attribute__((ext_vector_type(8)));
typedef float  f32x4  __attribute__((ext_vector_type(4)));

// async global->LDS, 16B per lane; LDS dest = wave-uniform base + lane*16
#define GLD16(gp, lp) __builtin_amdgcn_global_load_lds( \
    (__attribute__((address_space(1))) const unsigned int*)(gp), \
    (__attribute__((address_space(3))) unsigned int*)(lp), 16, 0, 0)

__device__ __forceinline__ int soff(int l) { return l*(4*l*l-1)/3; }  // sum_{l'<l}(2l'+1)^2

__device__ __forceinline__ ushort_t f2bf(float x) {
  __hip_bfloat16 h = __float2bfloat16(x);
  return *reinterpret_cast<ushort_t*>(&h);
}
__device__ __forceinline__ float bf2f(ushort_t u) {
  __hip_bfloat16 h = *reinterpret_cast<__hip_bfloat16*>(&u);
  return __bfloat162float(h);
}

// ================= device building blocks for the fused prep kernel =================

__device__ __forceinline__ void dev_gemm_nn(float* smem,
    const float* __restrict__ A, const float* __restrict__ B, float* __restrict__ C,
    int M, int N, int K, int lda, int ldb, int ldc, float alpha, int bx, int by)
{
  float* As = smem;
  float* Bs = smem + 32*68;
  const int tid = threadIdx.x;
  const int tx = tid & 15, ty = tid >> 4;
  const int n0 = bx * 64, m0 = by * 64;
  float acc[4][4] = {};
  for (int k0 = 0; k0 < K; k0 += 32) {
    {
      const int kk = tid & 31, mmB = tid >> 5;
      #pragma unroll
      for (int j = 0; j < 8; ++j) {
        const int mm = mmB + 8*j;
        const int m = m0 + mm, k = k0 + kk;
        As[kk*68 + mm] = (m < M && k < K) ? A[(size_t)m*lda + k] : 0.f;
      }
    }
    {
      const int nn = tid & 63, kkB = tid >> 6;
      #pragma unroll
      for (int j = 0; j < 8; ++j) {
        const int kk = kkB + 4*j;
        const int n = n0 + nn, k = k0 + kk;
        Bs[kk*68 + nn] = (n < N && k < K) ? B[(size_t)k*ldb + n] : 0.f;
      }
    }
    __syncthreads();
    #pragma unroll
    for (int kk = 0; kk < 32; ++kk) {
      const float4 a4 = *(const float4*)&As[kk*68 + ty*4];
      const float4 b4 = *(const float4*)&Bs[kk*68 + tx*4];
      const float av[4] = {a4.x,a4.y,a4.z,a4.w};
      const float bv[4] = {b4.x,b4.y,b4.z,b4.w};
      #pragma unroll
      for (int i = 0; i < 4; ++i)
        #pragma unroll
        for (int j = 0; j < 4; ++j)
          acc[i][j] = fmaf(av[i], bv[j], acc[i][j]);
    }
    __syncthreads();
  }
  #pragma unroll
  for (int i = 0; i < 4; ++i) {
    const int m = m0 + ty*4 + i;
    if (m >= M) continue;
    #pragma unroll
    for (int j = 0; j < 4; ++j) {
      const int n = n0 + tx*4 + j;
      if (n >= N) continue;
      C[(size_t)m*ldc + n] = acc[i][j] * alpha;
    }
  }
}

__device__ __forceinline__ void dev_transpose_cvt(float* smem,
    const float* __restrict__ in, int R, int C,
    ushort_t* __restrict__ out, int Rp, int Cp, int bx, int by)
{
  float (*t)[33] = (float(*)[33])smem;
  const int c0 = bx*32, r0 = by*32;
  const int tx = threadIdx.x & 31, ty = threadIdx.x >> 5;
  #pragma unroll
  for (int j = 0; j < 4; ++j) {
    const int r = r0 + ty + j*8, c = c0 + tx;
    t[ty + j*8][tx] = (r < R && c < C) ? in[(size_t)r*C + c] : 0.f;
  }
  __syncthreads();
  #pragma unroll
  for (int j = 0; j < 4; ++j) {
    const int c = c0 + ty + j*8, r = r0 + tx;
    if (c < Cp && r < Rp) out[(size_t)c*Rp + r] = f2bf(t[tx][ty + j*8]);
  }
}

__device__ __forceinline__ void dev_transpose_fmap(float* smem,
    const float* __restrict__ fmap, ushort_t* __restrict__ out, int cc, int b)
{
  float* Fs = smem;   // [c_local][h], 64*49
  const int tid = threadIdx.x;
  const int c0 = cc*64;
  const float* fsrc = fmap + ((size_t)b*CENC + c0)*HW;
  for (int idx = tid; idx < 784; idx += 256)
    *(float4*)&Fs[idx*4] = *(const float4*)&fsrc[idx*4];
  __syncthreads();
  for (int idx = tid; idx < 3136; idx += 256) {
    const int h = idx >> 6, cl = idx & 63;
    out[(size_t)(b*49 + h)*CENC + c0 + cl] = f2bf(Fs[cl*49 + h]);
  }
}

__device__ __forceinline__ void dev_sumP(float* smem,
    const float* __restrict__ proj_w, const float* __restrict__ proj_Y,
    float* __restrict__ sumP)
{
  float* colsum = smem;   // 192 floats
  const int tid = threadIdx.x;
  if (tid < 192) {
    float s = 0.f;
    for (int h = 0; h < 49; ++h) s += proj_w[h*192 + tid];
    colsum[tid] = s;
  }
  __syncthreads();
  if (tid < 64) {
    float s = 0.f;
    if (tid < 49) for (int k = 0; k < 192; ++k) s += colsum[k] * proj_Y[k*49 + tid];
    sumP[tid] = (tid < 49) ? s * 0.07216878364870323f : 0.f;
  }
}

// ================= fused prep kernel =================
__global__ __launch_bounds__(256) void prep_all(
    const float* __restrict__ fmap, const float* __restrict__ conv_w,
    const float* __restrict__ proj_w, const float* __restrict__ proj_Y,
    const float* __restrict__ fs_w, const float* __restrict__ fs_Y,
    const float* __restrict__ act_to, const float* __restrict__ act_from,
    const float* __restrict__ so3_w, const float* __restrict__ so3_D,
    float* __restrict__ wP, float* __restrict__ wSumP, float* __restrict__ wPsi2,
    float* __restrict__ wPsiP,
    ushort_t* __restrict__ actToT, ushort_t* __restrict__ actFromT,
    ushort_t* __restrict__ cwT, ushort_t* __restrict__ fmapT)
{
  __shared__ float smem[32*68*2];
  const int blk = blockIdx.x;
  const float is192 = 0.07216878364870323f;
  if (blk < 1) {
    dev_gemm_nn(smem, proj_w, proj_Y, wP, 49,49,192, 192,49,49, is192, 0, 0);
  } else if (blk < 9) {
    dev_gemm_nn(smem, so3_w, so3_D, wPsi2, 8,455,192, 192,455,455, is192, blk-1, 0);
  } else if (blk < 73) {
    dev_gemm_nn(smem, fs_w, fs_Y, wPsiP, 4096,49,192, 192,49,128, is192, 0, blk-9);
  } else if (blk < 2121) {
    const int t = blk-73;   dev_transpose_cvt(smem, act_to, 455, 4000, actToT, 512, 4096, t & 127, t >> 7);
  } else if (blk < 4169) {
    const int t = blk-2121; dev_transpose_cvt(smem, act_from, 4000, 455, actFromT, 4096, 512, t & 15, t >> 4);
  } else if (blk < 5193) {
    const int t = blk-4169; dev_transpose_cvt(smem, conv_w, 512, 2048, cwT, 512, 2048, t & 63, t >> 6);
  } else if (blk < 9289) {
    const int t = blk-5193; dev_transpose_fmap(smem, fmap, fmapT, t & 31, t >> 5);
  } else {
    dev_sumP(smem, proj_w, proj_Y, wSumP);
  }
}

// ============ psiT cvt + bpsi ============
__global__ __launch_bounds__(256) void psiT_bpsi(
    const float* __restrict__ wPsiP, const float* __restrict__ conv_b,
    ushort_t* __restrict__ psiT, float* __restrict__ bpsi)
{
  const int blk = blockIdx.x, tid = threadIdx.x;
  if (blk < 1024) {
    const int idx = blk*256 + tid;
    const int row = idx >> 9, f = idx & 511;
    const int g = row >> 6, ii = row & 63;
    psiT[idx] = (ii < 49) ? f2bf(wPsiP[(size_t)(f*8 + g)*128 + ii]) : (ushort_t)0;
  } else {
    const int w = tid >> 6, lane = tid & 63;
    const int gi = (blk-1024)*4 + w;
    const int g = gi >> 6, ii = gi & 63;
    float s = 0.f;
    if (ii < 49) {
      #pragma unroll
      for (int s8 = 0; s8 < 8; ++s8) {
        const int f = s8*64 + lane;
        s += conv_b[f] * bf2f(f2bf(wPsiP[(size_t)(f*8 + g)*128 + ii]));
      }
    }
    #pragma unroll
    for (int off = 32; off; off >>= 1) s += __shfl_down(s, off);
    if (lane == 0) bpsi[gi] = s;
  }
}

// ---------- bf16 MFMA NT GEMM, m97-style async staging ----------
// Tile M=64 x N=128, BK=64, 4 waves (256 thr), wave-tile 64x32 (acc[4][2]).
// Staging: global_load_lds 16B/lane direct to LDS; XOR granule swizzle
// (lane fetches global granule (lane&7)^(row&7); LDS rows contiguous 128B) keeps
// global loads coalesced AND fragment ds_read_b128 <=2-way bank-conflict (free).
// mode 0: fp32 store | mode 1: relu->bf16 | mode 2: split-K fp32 partials | mode 3: bf16
__global__ __launch_bounds__(256) void gemm4_nt(
    const ushort_t* __restrict__ A, const ushort_t* __restrict__ B, void* __restrict__ Cv,
    int M, int N, int K, int lda, int ldb, int ldc,
    int mode, int kPartLen)
{
  __shared__ ushort_t Alds[64*64];    // 8 KB : 64 rows x 64 k
  __shared__ ushort_t Blds[128*64];   // 16 KB: 128 rows x 64 k
  const int tid = threadIdx.x;
  const int wv = tid >> 6, ln = tid & 63;
  const int col = ln & 15, quad = ln >> 4;
  const int m0 = blockIdx.y * 64, n0 = blockIdx.x * 128;
  int kStart = 0, kEnd = K;
  float*    C  = (float*)Cv;
  ushort_t* Cb = (ushort_t*)Cv;
  if (mode == 2) {
    kStart = blockIdx.z * kPartLen;
    kEnd = min(K, kStart + kPartLen);
    C += (size_t)blockIdx.z * (size_t)M * (size_t)ldc;
  }

  // staging addresses (advance by 64 elements per k-iter)
  const int rl = ln >> 3;          // row within 8-row group
  const int gsw = (ln & 7) ^ rl;   // swizzled granule to FETCH (row&7 == rl)
  const ushort_t* aP[2]; const ushort_t* bP[4];
  ushort_t* aL[2]; ushort_t* bL[4];
  #pragma unroll
  for (int r = 0; r < 2; ++r) {
    const int R = wv*16 + r*8;
    aP[r] = A + (size_t)(m0 + R + rl)*lda + kStart + gsw*8;
    aL[r] = &Alds[R*64];           // wave-uniform
  }
  #pragma unroll
  for (int r = 0; r < 4; ++r) {
    const int R = wv*32 + r*8;
    bP[r] = B + (size_t)(n0 + R + rl)*ldb + kStart + gsw*8;
    bL[r] = &Blds[R*64];
  }

  f32x4 acc[4][2];
  #pragma unroll
  for (int i = 0; i < 4; ++i)
    #pragma unroll
    for (int j = 0; j < 2; ++j)
      acc[i][j] = (f32x4){0.f,0.f,0.f,0.f};

  for (int k0 = kStart; k0 < kEnd; k0 += 64) {
    #pragma unroll
    for (int r = 0; r < 2; ++r) { GLD16(aP[r], aL[r]); aP[r] += 64; }
    #pragma unroll
    for (int r = 0; r < 4; ++r) { GLD16(bP[r], bL[r]); bP[r] += 64; }
    __syncthreads();
    #pragma unroll
    for (int ks = 0; ks < 2; ++ks) {
      bf16x8 af[4], bfr[2];
      #pragma unroll
      for (int i = 0; i < 4; ++i) {
        const int row = i*16 + col;
        af[i] = *(bf16x8*)&Alds[row*64 + (((ks*4 + quad) ^ (row & 7)) << 3)];
      }
      #pragma unroll
      for (int j = 0; j < 2; ++j) {
        const int row = wv*32 + j*16 + col;
        bfr[j] = *(bf16x8*)&Blds[row*64 + (((ks*4 + quad) ^ (row & 7)) << 3)];
      }
      #pragma unroll
      for (int i = 0; i < 4; ++i)
        #pragma unroll
        for (int j = 0; j < 2; ++j)
          acc[i][j] = __builtin_amdgcn_mfma_f32_16x16x32_bf16(af[i], bfr[j], acc[i][j], 0, 0, 0);
    }
    __syncthreads();
  }

  // epilogue: C/D layout col = lane&15 (n), row = quad*4 + reg (m)
  #pragma unroll
  for (int i = 0; i < 4; ++i) {
    const int mBase = m0 + i*16 + quad*4;
    #pragma unroll
    for (int j = 0; j < 2; ++j) {
      const int n = n0 + wv*32 + j*16 + col;
      if (mode == 1) {
        #pragma unroll
        for (int r = 0; r < 4; ++r)
          Cb[(size_t)(mBase+r)*ldc + n] = f2bf(fmaxf(acc[i][j][r], 0.f));
      } else if (mode == 3) {
        #pragma unroll
        for (int r = 0; r < 4; ++r)
          Cb[(size_t)(mBase+r)*ldc + n] = f2bf(acc[i][j][r]);
      } else {
        #pragma unroll
        for (int r = 0; r < 4; ++r)
          C[(size_t)(mBase+r)*ldc + n] = acc[i][j][r];
      }
    }
  }
}

// ---------- gather_y: P-contraction + block-diag gather + rank-1 bias + 1/sqrt(512) ----------
__global__ __launch_bounds__(256) void gather_y(
    const float* __restrict__ T, const float* __restrict__ P,
    const float* __restrict__ sumP, const float* __restrict__ bpsi,
    ushort_t* __restrict__ y)
{
  __shared__ float Tg[49*64];
  __shared__ float Pl[49*49];
  __shared__ float sPl[49];
  __shared__ float bps[64];
  const int tid = threadIdx.x;
  const int g = blockIdx.x & 7, b = blockIdx.x >> 3;
  for (int idx = tid; idx < 49*64; idx += 256) {
    const int h = idx >> 6, c = idx & 63;
    Tg[idx] = T[(size_t)(b*49 + h)*512 + g*64 + c];
  }
  for (int idx = tid; idx < 2401; idx += 256) Pl[idx] = P[idx];
  if (tid < 49) sPl[tid] = sumP[tid];
  if (tid < 64) bps[tid] = bpsi[g*64 + tid];
  __syncthreads();
  #pragma unroll
  for (int rr = 0; rr < 2; ++rr) {
    const int j = tid + rr*256;
    float v = 0.f;
    if (j < SO3D) {
      int l;
      if (j < 1) l = 0; else if (j < 10) l = 1; else if (j < 35) l = 2;
      else if (j < 84) l = 3; else if (j < 165) l = 4; else if (j < 286) l = 5; else l = 6;
      const int so = soff(l), d = 2*l+1;
      const int r = j - so;
      const int u = r / d, m = r - u*d;
      const int i = l*l + m, colT = l*l + u;
      float acc = 0.f;
      #pragma unroll 7
      for (int h = 0; h < 49; ++h)
        acc = fmaf(Pl[h*49 + i], Tg[h*64 + colT], acc);
      v = (acc + sPl[i]*bps[colT]) * 0.044194173824159216f;
    }
    y[(size_t)(b*8+g)*512 + j] = f2bf(v);
  }
}

// ---------- final so3 conv: 8-partial sum + per-l contraction + fp32 store ----------
__global__ __launch_bounds__(512) void so3_final(
    const float* __restrict__ zpart, const float* __restrict__ psi2,
    float* __restrict__ out)
{
  __shared__ float Zs[8*SO3D];
  __shared__ float P2s[8*SO3D];
  const int b = blockIdx.x, tid = threadIdx.x;
  for (int idx = tid; idx < 8*SO3D; idx += 512) {
    const int f = idx / SO3D, i = idx - f*SO3D;
    float s = 0.f;
    #pragma unroll
    for (int p = 0; p < 8; ++p)
      s += zpart[((size_t)p*1024 + (size_t)b*FHID + f)*512 + i];
    Zs[idx] = s;
    P2s[idx] = psi2[idx];
  }
  __syncthreads();
  if (tid < SO3D) {
    const int i = tid;
    int l;
    if (i < 1) l = 0; else if (i < 10) l = 1; else if (i < 35) l = 2;
    else if (i < 84) l = 3; else if (i < 165) l = 4; else if (i < 286) l = 5; else l = 6;
    const int so = soff(l), d = 2*l+1;
    const int r = i - so;
    const int v = r / d, m = r - v*d;
    float acc = 0.f;
    for (int f = 0; f < 8; ++f)
      for (int u = 0; u < d; ++u)
        acc = fmaf(Zs[f*SO3D + so + u*d + m], P2s[f*SO3D + so + u*d + v], acc);
    const float scale = rsqrtf(8.0f * (float)d);
    out[(size_t)b*SO3D + i] = acc * scale;
  }
}

extern "C" void kernel_launch(void* const* d_in, const int* in_sizes, int n_in,
                              void* d_out, int out_size, void* d_ws, size_t ws_size,
                              hipStream_t stream) {
  const float* fmap    = (const float*)d_in[0];
  const float* conv_w  = (const float*)d_in[1];
  const float* conv_b  = (const float*)d_in[2];
  const float* proj_w  = (const float*)d_in[3];
  const float* proj_Y  = (const float*)d_in[4];
  const float* fs_w    = (const float*)d_in[5];
  const float* fs_Y    = (const float*)d_in[6];
  const float* act_to  = (const float*)d_in[7];
  const float* act_from= (const float*)d_in[8];
  const float* so3_w   = (const float*)d_in[9];
  const float* so3_D   = (const float*)d_in[10];
  float* out           = (float*)d_out;

  // workspace (bytes), lifetime-packed; max ~54.8 MB (known-good size)
  char* wsb = (char*)d_ws;
  float*    wP       = (float*)(wsb + 0);           // 49x49 fp32
  float*    wSumP    = (float*)(wsb + 9728);        // 64 fp32
  float*    wPsi2    = (float*)(wsb + 9984);        // 8x455 fp32 -> 24544, pad 24576
  ushort_t* actToT   = (ushort_t*)(wsb + 24576);    // 4096x512 bf16 -> 4218880
  ushort_t* actFromT = (ushort_t*)(wsb + 4218880);  // 512x4096 bf16 -> 8413184
  ushort_t* yPad     = (ushort_t*)(wsb + 8413184);  // 1024x512 bf16 -> 9461760
  ushort_t* psiT     = (ushort_t*)(wsb + 9461760);  // 512x512 bf16 -> 9986048
  float*    bpsi     = (float*)(wsb + 9986048);     // 512 fp32 -> 9988096
  ushort_t* W2T      = (ushort_t*)(wsb + 9988096);  // 512x2048 bf16 -> 12085248
  ushort_t* fmapT    = (ushort_t*)(wsb + 12085248); // 6272x2048 bf16 -> 37775360 (dead after T gemm)
  float*    wPsiP    = (float*)(wsb + 37775360);    // 4096x128 fp32 -> 39872512 (dead after psiT_bpsi)
  ushort_t* cwT      = (ushort_t*)(wsb + 39872512); // 2048x512 bf16 -> 41969664 (dead after W2T gemm)
  float*    Tbuf     = (float*)(wsb + 41969664);    // 6272x512 fp32 -> 54814720
  // aliases into dead fmapT region:
  ushort_t* gBuf     = (ushort_t*)(wsb + 12085248); // 1024x4096 bf16 -> 20473856
  float*    zPart    = (float*)(wsb + 20473856);    // 8x1024x512 fp32 -> 37251072

  // 1) ALL independent prep in one dispatch
  prep_all<<<dim3(9290), 256, 0, stream>>>(
      fmap, conv_w, proj_w, proj_Y, fs_w, fs_Y, act_to, act_from, so3_w, so3_D,
      wP, wSumP, wPsi2, wPsiP, actToT, actFromT, cwT, fmapT);
  // 2) psiT cvt + bpsi
  psiT_bpsi<<<dim3(1152), 256, 0, stream>>>(wPsiP, conv_b, psiT, bpsi);
  // 3) W2T[gi][c] = psiT @ cwT^T   (M=512, N=2048, K=512), bf16 out
  gemm4_nt<<<dim3(16,8), 256, 0, stream>>>(psiT, cwT, W2T,
      512, 2048, 512, 512, 512, 2048, 3, 0);
  // 4) T[(b,h)][gi] = fmapT @ W2T^T  (M=6272, N=512, K=2048), fp32 out, grid 4x98
  gemm4_nt<<<dim3(4,98), 256, 0, stream>>>(fmapT, W2T, Tbuf,
      6272, 512, 2048, 2048, 2048, 512, 0, 0);
  // 5) yPad = P-contraction + block-diag gather + rank-1 bias + 1/sqrt(512)
  gather_y<<<dim3(1024), 256, 0, stream>>>(Tbuf, wP, wSumP, bpsi, yPad);
  // 6) g = relu(yPad @ actToT^T) bf16   (M=1024, N=4096, K=512)
  gemm4_nt<<<dim3(32,16), 256, 0, stream>>>(yPad, actToT, gBuf,
      1024, 4096, 512, 512, 512, 4096, 1, 0);
  // 7) zPart = gBuf @ actFromT^T, split-K=8 partial buffers  (M=1024, N=512, K=4096)
  gemm4_nt<<<dim3(4,16,8), 256, 0, stream>>>(gBuf, actFromT, zPart,
      1024, 512, 4096, 4096, 4096, 512, 2, 512);
  // 8) final contraction + fp32 store
  so3_final<<<dim3(128), 512, 0, stream>>>(zPart, wPsi2, out);
}